// Round 6
// baseline (891.139 us; speedup 1.0000x reference)
//
#include <hip/hip_runtime.h>

typedef unsigned int u32;

// ---- workspace layout (float offsets) ----
// Combined gate weights Wc = [WsG | WdG] as [64][512] (k-major, 512 cols).
#define WS_WSG   0        // 64x512 combined  (32768 floats)
#define WS_WEG   32768    // 8x256 : Wenc @ Wgate   [m][j]
#define WS_BALL  34816    // 256   : (benc+bsrc+bdst) @ Wgate + bgate
#define WS_GS    35328    // N x 512 interleaved: G[n][0..255]=GS, [256..511]=GD
// then: tbl (E float4, 16B aligned), then cnt (N ints)

// ---------------------------------------------------------------- zero out
__global__ void zero_k(float* p, int n) {
    int i = blockIdx.x * blockDim.x + threadIdx.x;
    int st = gridDim.x * blockDim.x;
    for (; i < n; i += st) p[i] = 0.0f;
}

// ---------------------------------------------------------------- compose weights
// 73 blocks x 256 threads. r<64: combined [WsG|WdG] row; 64..71: WeG; 72: bias.
__global__ void compose_k(const float* __restrict__ Wsrc, const float* __restrict__ Wdst,
                          const float* __restrict__ Wenc, const float* __restrict__ benc,
                          const float* __restrict__ bsrc, const float* __restrict__ bdst,
                          const float* __restrict__ Wgate, const float* __restrict__ bgate,
                          float* __restrict__ ws) {
    const int j = threadIdx.x;           // 0..255
    const int r = blockIdx.x;            // 0..72
    if (r < 64) {
        float a = 0.f, b = 0.f;
        for (int c = 0; c < 64; ++c) {
            const float wg = Wgate[c * 256 + j];
            a += Wsrc[r * 64 + c] * wg;
            b += Wdst[r * 64 + c] * wg;
        }
        ws[WS_WSG + r * 512 + j] = a;
        ws[WS_WSG + r * 512 + 256 + j] = b;
    } else if (r < 72) {
        const int m = r - 64;
        float a = 0.f;
        for (int c = 0; c < 64; ++c) a += Wenc[m * 64 + c] * Wgate[c * 256 + j];
        ws[WS_WEG + m * 256 + j] = a;
    } else {
        float a = bgate[j];
        for (int c = 0; c < 64; ++c)
            a += (benc[c] + bsrc[c] + bdst[c]) * Wgate[c * 256 + j];
        ws[WS_BALL + j] = a;
    }
}

// ---------------------------------------------------------------- node precompute v3
// (verified round 5) G[n][0..511] = emb[n][0..63] @ Wc[64][512].
__global__ __launch_bounds__(512, 1) void nodepre3_k(
    const float* __restrict__ emb, const float* __restrict__ Wc,
    float* __restrict__ G, int N) {
    __shared__ __align__(16) float sW[32768];    // 128 KB [k][512]
    __shared__ __align__(16) float sEm[1024];    // 16 node rows
    for (int i = threadIdx.x * 4; i < 32768; i += 2048)
        *(float4*)&sW[i] = *(const float4*)&Wc[i];

    const int c4 = (threadIdx.x & 127) << 2;
    const int g = threadIdx.x >> 7;
    const int lim = N * 64;
    const int ntiles = (N + 15) >> 4;

    for (int tile = blockIdx.x; tile < ntiles; tile += gridDim.x) {
        const int n0 = tile << 4;
        const int base = n0 * 64;
        __syncthreads();
        for (int i = threadIdx.x * 4; i < 1024; i += 2048) {
            const int gi = base + i;
            *(float4*)&sEm[i] = (gi < lim) ? *(const float4*)&emb[gi]
                                           : make_float4(0.f, 0.f, 0.f, 0.f);
        }
        __syncthreads();

        float4 a0 = {0,0,0,0}, a1 = {0,0,0,0}, a2 = {0,0,0,0}, a3 = {0,0,0,0};
        const float* e0p = &sEm[(g * 4 + 0) * 64];
        const float* e1p = &sEm[(g * 4 + 1) * 64];
        const float* e2p = &sEm[(g * 4 + 2) * 64];
        const float* e3p = &sEm[(g * 4 + 3) * 64];
        #pragma unroll 8
        for (int k = 0; k < 64; ++k) {
            const float4 w = *(const float4*)&sW[k * 512 + c4];
            const float e0 = e0p[k], e1 = e1p[k], e2 = e2p[k], e3 = e3p[k];
            a0.x += e0 * w.x; a0.y += e0 * w.y; a0.z += e0 * w.z; a0.w += e0 * w.w;
            a1.x += e1 * w.x; a1.y += e1 * w.y; a1.z += e1 * w.z; a1.w += e1 * w.w;
            a2.x += e2 * w.x; a2.y += e2 * w.y; a2.z += e2 * w.z; a2.w += e2 * w.w;
            a3.x += e3 * w.x; a3.y += e3 * w.y; a3.z += e3 * w.z; a3.w += e3 * w.w;
        }
        const int nb = n0 + g * 4;
        if (nb + 0 < N) *(float4*)&G[(size_t)(nb + 0) * 512 + c4] = a0;
        if (nb + 1 < N) *(float4*)&G[(size_t)(nb + 1) * 512 + c4] = a1;
        if (nb + 2 < N) *(float4*)&G[(size_t)(nb + 2) * 512 + c4] = a2;
        if (nb + 3 < N) *(float4*)&G[(size_t)(nb + 3) * 512 + c4] = a3;
    }
}

// ---------------------------------------------------------------- CSR: count
__global__ void count_k(const int* __restrict__ src, const int* __restrict__ dst,
                        int* __restrict__ cnt, int N, int E) {
    __shared__ int sFl[2];
    if (threadIdx.x == 0) {
        const u32* ps = (const u32*)src;
        const u32* pd = (const u32*)dst;
        int s64 = 1, d64 = 1;
        for (int i = 1; i < 128; i += 2) {
            if (ps[i] != 0u) s64 = 0;
            if (pd[i] != 0u) d64 = 0;
        }
        sFl[0] = s64;
        sFl[1] = d64;
    }
    __syncthreads();
    const int i64s = sFl[0], i64d = sFl[1];
    for (int e = blockIdx.x * blockDim.x + threadIdx.x; e < E;
         e += gridDim.x * blockDim.x) {
        const int s = i64s ? src[2 * e] : src[e];
        const int t = i64d ? dst[2 * e] : dst[e];
        if (s < 0 || s >= N || t < 0 || t >= N) continue;
        atomicAdd(&cnt[s], 1);
    }
}

// ---------------------------------------------------------------- CSR: scan
// Single block: cnt[] -> exclusive prefix (cursor). (verified round 2)
__global__ __launch_bounds__(1024) void scan_k(int* __restrict__ cnt, int N) {
    __shared__ int sp[1024];
    const int tid = threadIdx.x;
    const int chunk = (N + 1023) >> 10;
    const int beg = tid * chunk;
    int end = beg + chunk; if (end > N) end = N;
    int sum = 0;
    for (int i = beg; i < end; ++i) sum += cnt[i];
    sp[tid] = sum;
    __syncthreads();
    for (int off = 1; off < 1024; off <<= 1) {
        const int v = (tid >= off) ? sp[tid - off] : 0;
        __syncthreads();
        sp[tid] += v;
        __syncthreads();
    }
    int cur = (tid == 0) ? 0 : sp[tid - 1];
    for (int i = beg; i < end; ++i) {
        const int c = cnt[i];
        cnt[i] = cur;
        cur += c;
    }
}

// ---------------------------------------------------------------- CSR: fill
// tbl[pos] = {r0,r1,r2,dst-bits}, src-sorted. After this, cnt[n] = row end.
__global__ void fill_k(const int* __restrict__ src, const int* __restrict__ dst,
                       const float* __restrict__ r_ij, int* __restrict__ cursor,
                       float4* __restrict__ tbl, int N, int E) {
    __shared__ int sFl[2];
    if (threadIdx.x == 0) {
        const u32* ps = (const u32*)src;
        const u32* pd = (const u32*)dst;
        int s64 = 1, d64 = 1;
        for (int i = 1; i < 128; i += 2) {
            if (ps[i] != 0u) s64 = 0;
            if (pd[i] != 0u) d64 = 0;
        }
        sFl[0] = s64;
        sFl[1] = d64;
    }
    __syncthreads();
    const int i64s = sFl[0], i64d = sFl[1];
    for (int e = blockIdx.x * blockDim.x + threadIdx.x; e < E;
         e += gridDim.x * blockDim.x) {
        const int s = i64s ? src[2 * e] : src[e];
        const int t = i64d ? dst[2 * e] : dst[e];
        if (s < 0 || s >= N || t < 0 || t >= N) continue;
        const float r0 = r_ij[e * 3 + 0];
        const float r1 = r_ij[e * 3 + 1];
        const float r2 = r_ij[e * 3 + 2];
        const int pos = atomicAdd(&cursor[s], 1);
        tbl[pos] = make_float4(r0, r1, r2, __int_as_float(t));
    }
}

// ---------------------------------------------------------------- edge kernel (CSR, no atomics)
// One wave per NODE, STRIDED over nodes: all 8192 in-flight waves sweep the
// same contiguous window of the src-sorted edge table (round-1's proven
// locality property) while each node's output is owned by one wave ->
// register accumulation + plain stores, zero atomics.
__global__ __launch_bounds__(256, 8) void edge_csr_k(
    const float* __restrict__ G, const float* __restrict__ z0g,
    const float* __restrict__ z1g, const int* __restrict__ rowend,
    const float4* __restrict__ tbl, const float* __restrict__ WeG,
    const float* __restrict__ ball, float* __restrict__ out, int N) {
    __shared__ float sWe[2048];   // 8 KB
    __shared__ float sBall[256];  // 1 KB
    for (int i = threadIdx.x; i < 2048; i += 256) sWe[i] = WeG[i];
    sBall[threadIdx.x] = ball[threadIdx.x];
    __syncthreads();

    const int wid = threadIdx.x >> 6, lane = threadIdx.x & 63;
    const int w = blockIdx.x * 4 + wid;
    const int nw = gridDim.x * 4;

    const float bl0 = sBall[lane], bl1 = sBall[64 + lane];
    const float bl2 = sBall[128 + lane], bl3 = sBall[192 + lane];

    for (int n = w; n < N; n += nw) {
        const int beg = (n == 0) ? 0 : rowend[n - 1];
        const int end = rowend[n];

        const float* gs = G + (size_t)n * 512 + lane;
        const float gsb0 = gs[0]   + bl0;
        const float gsb1 = gs[64]  + bl1;
        const float gsb2 = gs[128] + bl2;
        const float gsb3 = gs[192] + bl3;

        float accS = 0.f, accV0 = 0.f, accV1 = 0.f, accV2 = 0.f;

        for (int i = beg; i < end; ++i) {
            const float4 mt = tbl[i];           // sequential, wave-uniform
            const int t = __float_as_int(mt.w);
            const float r0 = mt.x, r1 = mt.y, r2 = mt.z;

            const float* gd = G + (size_t)t * 512 + 256 + lane;
            const float b0 = gd[0], b1 = gd[64], b2 = gd[128], b3 = gd[192];
            const float z0v = z0g[t * 64 + lane];
            const float* zp = z1g + t * 192 + lane;
            const float za = zp[0], zb = zp[64], zc = zp[128];

            float g0 = gsb0 + b0;
            float g1 = gsb1 + b1;
            float g2 = gsb2 + b2;
            float g3 = gsb3 + b3;

            const float d = sqrtf(r0 * r0 + r1 * r1 + r2 * r2);
            #pragma unroll
            for (int m = 0; m < 8; ++m) {
                const float mu = 0.28571428571f * (float)m;   // linspace(0, 2, 8)
                const float tt = (d - mu) * 4.0f;             // / sigma, sigma = 0.25
                const float rm = __expf(-tt * tt);
                const float* wq = &sWe[(m << 8) + lane];
                g0 += rm * wq[0];
                g1 += rm * wq[64];
                g2 += rm * wq[128];
                g3 += rm * wq[192];
            }

            const float v0 = r0 * 3.5f, v1 = r1 * 3.5f, v2 = r2 * 3.5f;
            const float inv = rsqrtf(1.0f + v0 * v0 + v1 * v1 + v2 * v2);
            const float h0 = v0 * inv, h1 = v1 * inv, h2 = v2 * inv;
            const float uu = h0 * za + h1 * zb + h2 * zc;

            accS  += g0 * z0v + g1 * uu;
            accV0 += g2 * za + g3 * h0 * z0v;
            accV1 += g2 * zb + g3 * h1 * z0v;
            accV2 += g2 * zc + g3 * h2 * z0v;
        }

        out[n * 64 + lane] = accS;              // plain stores: wave owns node n
        const int bo = N * 64 + n * 192 + lane;
        out[bo] = accV0;
        out[bo + 64] = accV1;
        out[bo + 128] = accV2;
    }
}

// ---------------------------------------------------------------- edge kernel (fast, fallback)
// round-1 structure (proven 440-453 us), G interleaved [n][512].
__global__ __launch_bounds__(256, 8) void edge_fast_k(
    const int* __restrict__ src, const int* __restrict__ dst,
    const float* __restrict__ r_ij, const float* __restrict__ z0g,
    const float* __restrict__ z1g, const float* __restrict__ G,
    const float* __restrict__ WeG, const float* __restrict__ ball,
    float* __restrict__ out, int N, int E) {
    __shared__ float sWe[2048];
    __shared__ float sBall[256];
    __shared__ int sFl[2];

    if (threadIdx.x == 0) {
        const u32* ps = (const u32*)src;
        const u32* pd = (const u32*)dst;
        int s64 = 1, d64 = 1;
        for (int i = 1; i < 128; i += 2) {
            if (ps[i] != 0u) s64 = 0;
            if (pd[i] != 0u) d64 = 0;
        }
        sFl[0] = s64;
        sFl[1] = d64;
    }
    for (int i = threadIdx.x; i < 2048; i += 256) sWe[i] = WeG[i];
    sBall[threadIdx.x] = ball[threadIdx.x];
    __syncthreads();

    const int wid = threadIdx.x >> 6, lane = threadIdx.x & 63;
    const int i64s = sFl[0], i64d = sFl[1];

    for (int e = blockIdx.x * 4 + wid; e < E; e += gridDim.x * 4) {
        const int s = i64s ? src[2 * e] : src[e];
        const int t = i64d ? dst[2 * e] : dst[e];
        if (s < 0 || s >= N || t < 0 || t >= N) continue;

        const float* gs = G + (size_t)s * 512 + lane;
        const float* gd = G + (size_t)t * 512 + 256 + lane;
        const float a0 = gs[0], a1 = gs[64], a2 = gs[128], a3 = gs[192];
        const float b0 = gd[0], b1 = gd[64], b2 = gd[128], b3 = gd[192];
        const float z0v = z0g[t * 64 + lane];
        const float za = z1g[t * 192 + lane];
        const float zb = z1g[t * 192 + 64 + lane];
        const float zc = z1g[t * 192 + 128 + lane];
        const float r0 = r_ij[e * 3 + 0];
        const float r1 = r_ij[e * 3 + 1];
        const float r2 = r_ij[e * 3 + 2];

        float g0 = a0 + b0 + sBall[lane];
        float g1 = a1 + b1 + sBall[64 + lane];
        float g2 = a2 + b2 + sBall[128 + lane];
        float g3 = a3 + b3 + sBall[192 + lane];

        const float d = sqrtf(r0 * r0 + r1 * r1 + r2 * r2);
        #pragma unroll
        for (int m = 0; m < 8; ++m) {
            const float mu = 0.28571428571f * (float)m;
            const float tt = (d - mu) * 4.0f;
            const float rm = __expf(-tt * tt);
            const float* wq = &sWe[(m << 8) + lane];
            g0 += rm * wq[0];
            g1 += rm * wq[64];
            g2 += rm * wq[128];
            g3 += rm * wq[192];
        }

        const float v0 = r0 * 3.5f, v1 = r1 * 3.5f, v2 = r2 * 3.5f;
        const float inv = rsqrtf(1.0f + v0 * v0 + v1 * v1 + v2 * v2);
        const float h0 = v0 * inv, h1 = v1 * inv, h2 = v2 * inv;
        const float uu = h0 * za + h1 * zb + h2 * zc;

        const float smsg = g0 * z0v + g1 * uu;
        const float vm0 = g2 * za + g3 * h0 * z0v;
        const float vm1 = g2 * zb + g3 * h1 * z0v;
        const float vm2 = g2 * zc + g3 * h2 * z0v;

        atomicAdd(&out[s * 64 + lane], smsg);
        const int bo = N * 64 + s * 192 + lane;
        atomicAdd(&out[bo], vm0);
        atomicAdd(&out[bo + 64], vm1);
        atomicAdd(&out[bo + 128], vm2);
    }
}

// ---------------------------------------------------------------- node epilogue v3
// (verified round 5) out = (4N)x64 row-major; rows<N use Ws else Wv. In-place.
__global__ __launch_bounds__(256, 3) void nodepost3_k(
    float* __restrict__ out, const float* __restrict__ Ws,
    const float* __restrict__ Wv, int N) {
    __shared__ __align__(16) float sW[8192];
    __shared__ float sR[64 * 65];
    for (int i = threadIdx.x * 4; i < 8192; i += 1024) {
        *(float4*)&sW[i] = (i < 4096) ? *(const float4*)&Ws[i]
                                      : *(const float4*)&Wv[i - 4096];
    }
    const int c4 = (threadIdx.x & 15) << 2;
    const int rq = threadIdx.x >> 4;
    const int totalRows = 4 * N;
    const int lim = totalRows * 64;
    const int ntiles = (totalRows + 63) >> 6;

    for (int tile = blockIdx.x; tile < ntiles; tile += gridDim.x) {
        const int r0 = tile << 6;
        __syncthreads();
        for (int i = threadIdx.x; i < 4096; i += 256) {
            const int gi = r0 * 64 + i;
            sR[(i >> 6) * 65 + (i & 63)] = (gi < lim) ? out[gi] : 0.f;
        }
        __syncthreads();

        const int rb = rq << 2;
        const int gr = r0 + rb;
        const int o0 = (gr + 0 < N) ? 0 : 4096;
        const int o3 = (gr + 3 < N) ? 0 : 4096;
        float4 a0 = {0,0,0,0}, a1 = {0,0,0,0}, a2 = {0,0,0,0}, a3 = {0,0,0,0};
        const float* rp0 = &sR[(rb + 0) * 65];
        const float* rp1 = &sR[(rb + 1) * 65];
        const float* rp2 = &sR[(rb + 2) * 65];
        const float* rp3 = &sR[(rb + 3) * 65];
        if (o0 == o3) {
            const float* wb = &sW[o0 + c4];
            #pragma unroll 8
            for (int k = 0; k < 64; ++k) {
                const float4 w = *(const float4*)&wb[k * 64];
                const float e0 = rp0[k], e1 = rp1[k], e2 = rp2[k], e3 = rp3[k];
                a0.x += e0 * w.x; a0.y += e0 * w.y; a0.z += e0 * w.z; a0.w += e0 * w.w;
                a1.x += e1 * w.x; a1.y += e1 * w.y; a1.z += e1 * w.z; a1.w += e1 * w.w;
                a2.x += e2 * w.x; a2.y += e2 * w.y; a2.z += e2 * w.z; a2.w += e2 * w.w;
                a3.x += e3 * w.x; a3.y += e3 * w.y; a3.z += e3 * w.z; a3.w += e3 * w.w;
            }
        } else {
            const int o1 = (gr + 1 < N) ? 0 : 4096;
            const int o2 = (gr + 2 < N) ? 0 : 4096;
            #pragma unroll 4
            for (int k = 0; k < 64; ++k) {
                const float4 w0 = *(const float4*)&sW[o0 + k * 64 + c4];
                const float4 w1 = *(const float4*)&sW[o1 + k * 64 + c4];
                const float4 w2 = *(const float4*)&sW[o2 + k * 64 + c4];
                const float4 w3 = *(const float4*)&sW[o3 + k * 64 + c4];
                const float e0 = rp0[k], e1 = rp1[k], e2 = rp2[k], e3 = rp3[k];
                a0.x += e0 * w0.x; a0.y += e0 * w0.y; a0.z += e0 * w0.z; a0.w += e0 * w0.w;
                a1.x += e1 * w1.x; a1.y += e1 * w1.y; a1.z += e1 * w1.z; a1.w += e1 * w1.w;
                a2.x += e2 * w2.x; a2.y += e2 * w2.y; a2.z += e2 * w2.z; a2.w += e2 * w2.w;
                a3.x += e3 * w3.x; a3.y += e3 * w3.y; a3.z += e3 * w3.z; a3.w += e3 * w3.w;
            }
        }
        if (gr + 0 < totalRows) *(float4*)&out[(size_t)(gr + 0) * 64 + c4] = a0;
        if (gr + 1 < totalRows) *(float4*)&out[(size_t)(gr + 1) * 64 + c4] = a1;
        if (gr + 2 < totalRows) *(float4*)&out[(size_t)(gr + 2) * 64 + c4] = a2;
        if (gr + 3 < totalRows) *(float4*)&out[(size_t)(gr + 3) * 64 + c4] = a3;
    }
}

// ---------------------------------------------------------------- full fallback
__global__ __launch_bounds__(512, 1) void edge_k(
    const int* __restrict__ src, const int* __restrict__ dst,
    const float* __restrict__ r_ij, const float* __restrict__ z0g,
    const float* __restrict__ z1g, const float* __restrict__ emb,
    const float* __restrict__ Wenc, const float* __restrict__ benc,
    const float* __restrict__ Wsrc, const float* __restrict__ bsrc,
    const float* __restrict__ Wdst, const float* __restrict__ bdst,
    const float* __restrict__ Wgate, const float* __restrict__ bgate,
    const float* __restrict__ Ws, const float* __restrict__ Wv,
    float* __restrict__ out, int N, int E)
{
    __shared__ float sWsrc[4096];
    __shared__ float sWdst[4096];
    __shared__ float sWg[16384];
    __shared__ float sWs[4096];
    __shared__ float sWv[4096];
    __shared__ float sWe[512];
    __shared__ float sB[64];
    __shared__ float sBg[256];
    __shared__ int sFl[2];

    if (threadIdx.x == 0) {
        const u32* ps = (const u32*)src;
        const u32* pd = (const u32*)dst;
        int s64 = 1, d64 = 1;
        for (int i = 1; i < 128; i += 2) {
            if (ps[i] != 0u) s64 = 0;
            if (pd[i] != 0u) d64 = 0;
        }
        sFl[0] = s64;
        sFl[1] = d64;
    }
    for (int i = threadIdx.x; i < 4096; i += 512) {
        sWsrc[i] = Wsrc[i];
        sWdst[i] = Wdst[i];
        sWs[i] = Ws[i];
        sWv[i] = Wv[i];
    }
    for (int i = threadIdx.x; i < 16384; i += 512) sWg[i] = Wgate[i];
    for (int i = threadIdx.x; i < 512; i += 512) sWe[i] = Wenc[i];
    if (threadIdx.x < 64)
        sB[threadIdx.x] = benc[threadIdx.x] + bsrc[threadIdx.x] + bdst[threadIdx.x];
    if (threadIdx.x < 256) sBg[threadIdx.x] = bgate[threadIdx.x];
    __syncthreads();

    const int wid = threadIdx.x >> 6, lane = threadIdx.x & 63;
    const int i64s = sFl[0], i64d = sFl[1];

    for (int e = blockIdx.x * 8 + wid; e < E; e += gridDim.x * 8) {
        const int s = i64s ? src[2 * e] : src[e];
        const int t = i64d ? dst[2 * e] : dst[e];
        if (s < 0 || s >= N || t < 0 || t >= N) continue;

        const float es = emb[s * 64 + lane];
        const float et = emb[t * 64 + lane];
        float de = sB[lane];
        #pragma unroll 8
        for (int k = 0; k < 64; ++k) {
            de += __shfl(es, k, 64) * sWsrc[(k << 6) + lane];
            de += __shfl(et, k, 64) * sWdst[(k << 6) + lane];
        }
        const float r0 = r_ij[e * 3 + 0];
        const float r1 = r_ij[e * 3 + 1];
        const float r2 = r_ij[e * 3 + 2];
        const float d = sqrtf(r0 * r0 + r1 * r1 + r2 * r2);
        #pragma unroll
        for (int m = 0; m < 8; ++m) {
            const float mu = (2.0f / 7.0f) * (float)m;
            const float tt = (d - mu) * 4.0f;
            de += __expf(-tt * tt) * sWe[m * 64 + lane];
        }

        const float v0 = r0 * 3.5f, v1 = r1 * 3.5f, v2 = r2 * 3.5f;
        const float inv = rsqrtf(1.0f + v0 * v0 + v1 * v1 + v2 * v2);
        const float h0 = v0 * inv, h1 = v1 * inv, h2 = v2 * inv;

        const float z0v = z0g[t * 64 + lane];
        const float za = z1g[t * 192 + lane];
        const float zb = z1g[t * 192 + 64 + lane];
        const float zc = z1g[t * 192 + 128 + lane];
        const float uu = h0 * za + h1 * zb + h2 * zc;

        float g0 = sBg[lane], g1 = sBg[64 + lane], g2 = sBg[128 + lane], g3 = sBg[192 + lane];
        #pragma unroll 8
        for (int k = 0; k < 64; ++k) {
            const float dk = __shfl(de, k, 64);
            const float* w = &sWg[(k << 8) + lane];
            g0 += dk * w[0];
            g1 += dk * w[64];
            g2 += dk * w[128];
            g3 += dk * w[192];
        }

        const float smsg = g0 * z0v + g1 * uu;
        const float vm0 = g2 * za + g3 * h0 * z0v;
        const float vm1 = g2 * zb + g3 * h1 * z0v;
        const float vm2 = g2 * zc + g3 * h2 * z0v;

        float p0 = 0.f, q0 = 0.f, q1 = 0.f, q2 = 0.f;
        #pragma unroll 8
        for (int k = 0; k < 64; ++k) {
            const float sk = __shfl(smsg, k, 64);
            const float a = __shfl(vm0, k, 64);
            const float b = __shfl(vm1, k, 64);
            const float c = __shfl(vm2, k, 64);
            p0 += sk * sWs[(k << 6) + lane];
            const float wv = sWv[(k << 6) + lane];
            q0 += a * wv;
            q1 += b * wv;
            q2 += c * wv;
        }

        atomicAdd(&out[s * 64 + lane], p0);
        const int b1 = N * 64 + s * 192 + lane;
        atomicAdd(&out[b1], q0);
        atomicAdd(&out[b1 + 64], q1);
        atomicAdd(&out[b1 + 128], q2);
    }
}

extern "C" void kernel_launch(void* const* d_in, const int* in_sizes, int n_in,
                              void* d_out, int out_size, void* d_ws, size_t ws_size,
                              hipStream_t stream) {
    const int* src = (const int*)d_in[0];
    const int* dst = (const int*)d_in[1];
    const float* r_ij = (const float*)d_in[2];
    const float* z0g  = (const float*)d_in[3];
    const float* z1g  = (const float*)d_in[4];
    const float* emb  = (const float*)d_in[5];
    const float* Wenc = (const float*)d_in[6];
    const float* benc = (const float*)d_in[7];
    const float* Wsrc = (const float*)d_in[8];
    const float* bsrc = (const float*)d_in[9];
    const float* Wdst = (const float*)d_in[10];
    const float* bdst = (const float*)d_in[11];
    const float* Wgate = (const float*)d_in[12];
    const float* bgate = (const float*)d_in[13];
    const float* Ws = (const float*)d_in[14];
    const float* Wv = (const float*)d_in[15];

    const int N = out_size / 256;                    // out0 N*64 + out1 N*192
    int E = in_sizes[0];
    if (in_sizes[2] / 3 < E) E = in_sizes[2] / 3;    // robustness

    float* ws = (float*)d_ws;
    const size_t gsz = (size_t)N * 512u;             // G floats
    const size_t needG   = ((size_t)WS_GS + gsz) * sizeof(float);
    const size_t tblOff  = (size_t)WS_GS + gsz;      // 16B-aligned (both mult of 4)
    const size_t cntOff  = tblOff + 4u * (size_t)E;
    const size_t needCSR = (cntOff + (size_t)N + 16u) * sizeof(float);

    if (ws != nullptr && ws_size >= needG) {
        compose_k<<<73, 256, 0, stream>>>(Wsrc, Wdst, Wenc, benc, bsrc, bdst,
                                          Wgate, bgate, ws);
        float* G = ws + WS_GS;
        nodepre3_k<<<256, 512, 0, stream>>>(emb, ws + WS_WSG, G, N);

        if (ws_size >= needCSR) {
            float4* tbl = (float4*)(ws + tblOff);
            int* cnt = (int*)(ws + cntOff);
            zero_k<<<64, 256, 0, stream>>>((float*)cnt, N);
            count_k<<<1024, 256, 0, stream>>>(src, dst, cnt, N, E);
            scan_k<<<1, 1024, 0, stream>>>(cnt, N);
            fill_k<<<1024, 256, 0, stream>>>(src, dst, r_ij, cnt, tbl, N, E);
            edge_csr_k<<<2048, 256, 0, stream>>>(G, z0g, z1g, cnt, tbl,
                                                 ws + WS_WEG, ws + WS_BALL,
                                                 (float*)d_out, N);
        } else {
            zero_k<<<2048, 256, 0, stream>>>((float*)d_out, out_size);
            edge_fast_k<<<2048, 256, 0, stream>>>(src, dst, r_ij, z0g, z1g, G,
                                                  ws + WS_WEG, ws + WS_BALL,
                                                  (float*)d_out, N, E);
        }
        nodepost3_k<<<2048, 256, 0, stream>>>((float*)d_out, Ws, Wv, N);
    } else {
        zero_k<<<2048, 256, 0, stream>>>((float*)d_out, out_size);
        edge_k<<<2048, 512, 0, stream>>>(src, dst, r_ij, z0g, z1g, emb, Wenc, benc,
                                         Wsrc, bsrc, Wdst, bdst, Wgate, bgate, Ws, Wv,
                                         (float*)d_out, N, E);
    }
}

// Round 7
// 749.833 us; speedup vs baseline: 1.1884x; 1.1884x over previous
//
#include <hip/hip_runtime.h>

typedef unsigned int u32;

// ---- workspace layout (float offsets) ----
// Combined gate weights Wc = [WsG | WdG] as [64][512] (k-major, 512 cols).
#define WS_WSG   0        // 64x512 combined  (32768 floats)
#define WS_WEG   32768    // 8x256 : Wenc @ Wgate   [m][j]
#define WS_BALL  34816    // 256   : (benc+bsrc+bdst) @ Wgate + bgate
#define WS_GS    35328    // N x 512 interleaved: G[n][0..255]=GS, [256..511]=GD

// ---------------------------------------------------------------- zero out
__global__ void zero_k(float* p, int n) {
    int i = blockIdx.x * blockDim.x + threadIdx.x;
    int st = gridDim.x * blockDim.x;
    for (; i < n; i += st) p[i] = 0.0f;
}

// ---------------------------------------------------------------- compose weights
// 73 blocks x 256 threads. r<64: combined [WsG|WdG] row; 64..71: WeG; 72: bias.
__global__ void compose_k(const float* __restrict__ Wsrc, const float* __restrict__ Wdst,
                          const float* __restrict__ Wenc, const float* __restrict__ benc,
                          const float* __restrict__ bsrc, const float* __restrict__ bdst,
                          const float* __restrict__ Wgate, const float* __restrict__ bgate,
                          float* __restrict__ ws) {
    const int j = threadIdx.x;           // 0..255
    const int r = blockIdx.x;            // 0..72
    if (r < 64) {
        float a = 0.f, b = 0.f;
        for (int c = 0; c < 64; ++c) {
            const float wg = Wgate[c * 256 + j];
            a += Wsrc[r * 64 + c] * wg;
            b += Wdst[r * 64 + c] * wg;
        }
        ws[WS_WSG + r * 512 + j] = a;
        ws[WS_WSG + r * 512 + 256 + j] = b;
    } else if (r < 72) {
        const int m = r - 64;
        float a = 0.f;
        for (int c = 0; c < 64; ++c) a += Wenc[m * 64 + c] * Wgate[c * 256 + j];
        ws[WS_WEG + m * 256 + j] = a;
    } else {
        float a = bgate[j];
        for (int c = 0; c < 64; ++c)
            a += (benc[c] + bsrc[c] + bdst[c]) * Wgate[c * 256 + j];
        ws[WS_BALL + j] = a;
    }
}

// ---------------------------------------------------------------- node precompute v3
// (verified round 5) G[n][0..511] = emb[n][0..63] @ Wc[64][512].
__global__ __launch_bounds__(512, 1) void nodepre3_k(
    const float* __restrict__ emb, const float* __restrict__ Wc,
    float* __restrict__ G, int N) {
    __shared__ __align__(16) float sW[32768];    // 128 KB [k][512]
    __shared__ __align__(16) float sEm[1024];    // 16 node rows
    for (int i = threadIdx.x * 4; i < 32768; i += 2048)
        *(float4*)&sW[i] = *(const float4*)&Wc[i];

    const int c4 = (threadIdx.x & 127) << 2;
    const int g = threadIdx.x >> 7;
    const int lim = N * 64;
    const int ntiles = (N + 15) >> 4;

    for (int tile = blockIdx.x; tile < ntiles; tile += gridDim.x) {
        const int n0 = tile << 4;
        const int base = n0 * 64;
        __syncthreads();
        for (int i = threadIdx.x * 4; i < 1024; i += 2048) {
            const int gi = base + i;
            *(float4*)&sEm[i] = (gi < lim) ? *(const float4*)&emb[gi]
                                           : make_float4(0.f, 0.f, 0.f, 0.f);
        }
        __syncthreads();

        float4 a0 = {0,0,0,0}, a1 = {0,0,0,0}, a2 = {0,0,0,0}, a3 = {0,0,0,0};
        const float* e0p = &sEm[(g * 4 + 0) * 64];
        const float* e1p = &sEm[(g * 4 + 1) * 64];
        const float* e2p = &sEm[(g * 4 + 2) * 64];
        const float* e3p = &sEm[(g * 4 + 3) * 64];
        #pragma unroll 8
        for (int k = 0; k < 64; ++k) {
            const float4 w = *(const float4*)&sW[k * 512 + c4];
            const float e0 = e0p[k], e1 = e1p[k], e2 = e2p[k], e3 = e3p[k];
            a0.x += e0 * w.x; a0.y += e0 * w.y; a0.z += e0 * w.z; a0.w += e0 * w.w;
            a1.x += e1 * w.x; a1.y += e1 * w.y; a1.z += e1 * w.z; a1.w += e1 * w.w;
            a2.x += e2 * w.x; a2.y += e2 * w.y; a2.z += e2 * w.z; a2.w += e2 * w.w;
            a3.x += e3 * w.x; a3.y += e3 * w.y; a3.z += e3 * w.z; a3.w += e3 * w.w;
        }
        const int nb = n0 + g * 4;
        if (nb + 0 < N) *(float4*)&G[(size_t)(nb + 0) * 512 + c4] = a0;
        if (nb + 1 < N) *(float4*)&G[(size_t)(nb + 1) * 512 + c4] = a1;
        if (nb + 2 < N) *(float4*)&G[(size_t)(nb + 2) * 512 + c4] = a2;
        if (nb + 3 < N) *(float4*)&G[(size_t)(nb + 3) * 512 + c4] = a3;
    }
}

// ---------------------------------------------------------------- edge kernel (ILP-2, strided)
// Round-1's proven strided traversal + 2-edge ILP: both edges' gathers issue
// up front; edge B's loads hide under edge A's consume. Pair (e, e+nw) with
// outer stride 2*nw keeps the cross-wave window contiguous (locality property
// that gives 759 MB fetch).
struct ER {
    int s, t;
    float ok;
    float r0, r1, r2;
    float a0, a1, a2, a3;     // GS row (+bias folded at consume)
    float b0, b1, b2, b3;     // GD row
    float z0, za, zb, zc;     // z0_j, z1_j rows
};

__device__ __forceinline__ ER load_edge(
    int e, int lane, int i64s, int i64d, int N,
    const int* __restrict__ src, const int* __restrict__ dst,
    const float* __restrict__ r_ij, const float* __restrict__ G,
    const float* __restrict__ z0g, const float* __restrict__ z1g) {
    ER x;
    int s = i64s ? src[2 * e] : src[e];
    int t = i64d ? dst[2 * e] : dst[e];
    x.ok = 1.f;
    if (s < 0 || s >= N) { s = 0; x.ok = 0.f; }
    if (t < 0 || t >= N) { t = 0; x.ok = 0.f; }
    x.s = s; x.t = t;
    x.r0 = r_ij[e * 3 + 0];
    x.r1 = r_ij[e * 3 + 1];
    x.r2 = r_ij[e * 3 + 2];
    const float* gs = G + (size_t)s * 512 + lane;
    x.a0 = gs[0]; x.a1 = gs[64]; x.a2 = gs[128]; x.a3 = gs[192];
    const float* gd = G + (size_t)t * 512 + 256 + lane;
    x.b0 = gd[0]; x.b1 = gd[64]; x.b2 = gd[128]; x.b3 = gd[192];
    x.z0 = z0g[t * 64 + lane];
    const float* zp = z1g + t * 192 + lane;
    x.za = zp[0]; x.zb = zp[64]; x.zc = zp[128];
    return x;
}

__device__ __forceinline__ void consume_edge(
    const ER& x, int lane, int N, const float* __restrict__ sWe,
    float bl0, float bl1, float bl2, float bl3, float* __restrict__ out) {
    float g0 = x.a0 + x.b0 + bl0;
    float g1 = x.a1 + x.b1 + bl1;
    float g2 = x.a2 + x.b2 + bl2;
    float g3 = x.a3 + x.b3 + bl3;

    const float d = sqrtf(x.r0 * x.r0 + x.r1 * x.r1 + x.r2 * x.r2);
    #pragma unroll
    for (int m = 0; m < 8; ++m) {
        const float mu = 0.28571428571f * (float)m;   // linspace(0, 2, 8)
        const float tt = (d - mu) * 4.0f;             // / sigma, sigma = 0.25
        const float rm = __expf(-tt * tt);
        const float* wq = &sWe[(m << 8) + lane];
        g0 += rm * wq[0];
        g1 += rm * wq[64];
        g2 += rm * wq[128];
        g3 += rm * wq[192];
    }

    const float v0 = x.r0 * 3.5f, v1 = x.r1 * 3.5f, v2 = x.r2 * 3.5f;
    const float inv = rsqrtf(1.0f + v0 * v0 + v1 * v1 + v2 * v2);
    const float h0 = v0 * inv, h1 = v1 * inv, h2 = v2 * inv;
    const float uu = h0 * x.za + h1 * x.zb + h2 * x.zc;

    const float smsg = (g0 * x.z0 + g1 * uu) * x.ok;
    const float vm0 = (g2 * x.za + g3 * h0 * x.z0) * x.ok;
    const float vm1 = (g2 * x.zb + g3 * h1 * x.z0) * x.ok;
    const float vm2 = (g2 * x.zc + g3 * h2 * x.z0) * x.ok;

    atomicAdd(&out[x.s * 64 + lane], smsg);
    const int bo = N * 64 + x.s * 192 + lane;
    atomicAdd(&out[bo], vm0);
    atomicAdd(&out[bo + 64], vm1);
    atomicAdd(&out[bo + 128], vm2);
}

__global__ __launch_bounds__(256, 8) void edge_ilp2_k(
    const int* __restrict__ src, const int* __restrict__ dst,
    const float* __restrict__ r_ij, const float* __restrict__ z0g,
    const float* __restrict__ z1g, const float* __restrict__ G,
    const float* __restrict__ WeG, const float* __restrict__ ball,
    float* __restrict__ out, int N, int E) {
    __shared__ float sWe[2048];   // 8 KB
    __shared__ float sBall[256];  // 1 KB
    __shared__ int sFl[2];

    if (threadIdx.x == 0) {
        const u32* ps = (const u32*)src;
        const u32* pd = (const u32*)dst;
        int s64 = 1, d64 = 1;
        for (int i = 1; i < 128; i += 2) {
            if (ps[i] != 0u) s64 = 0;
            if (pd[i] != 0u) d64 = 0;
        }
        sFl[0] = s64;
        sFl[1] = d64;
    }
    for (int i = threadIdx.x; i < 2048; i += 256) sWe[i] = WeG[i];
    sBall[threadIdx.x] = ball[threadIdx.x];
    __syncthreads();

    const int wid = threadIdx.x >> 6, lane = threadIdx.x & 63;
    const int i64s = sFl[0], i64d = sFl[1];
    const int nw = gridDim.x * 4;

    const float bl0 = sBall[lane], bl1 = sBall[64 + lane];
    const float bl2 = sBall[128 + lane], bl3 = sBall[192 + lane];

    for (int e = blockIdx.x * 4 + wid; e < E; e += 2 * nw) {
        const int e2 = e + nw;
        const bool hasB = e2 < E;                 // wave-uniform
        ER A = load_edge(e, lane, i64s, i64d, N, src, dst, r_ij, G, z0g, z1g);
        if (hasB) {
            ER B = load_edge(e2, lane, i64s, i64d, N, src, dst, r_ij, G, z0g, z1g);
            consume_edge(A, lane, N, sWe, bl0, bl1, bl2, bl3, out);
            consume_edge(B, lane, N, sWe, bl0, bl1, bl2, bl3, out);
        } else {
            consume_edge(A, lane, N, sWe, bl0, bl1, bl2, bl3, out);
        }
    }
}

// ---------------------------------------------------------------- node epilogue v3
// (verified round 5) out = (4N)x64 row-major; rows<N use Ws else Wv. In-place.
__global__ __launch_bounds__(256, 3) void nodepost3_k(
    float* __restrict__ out, const float* __restrict__ Ws,
    const float* __restrict__ Wv, int N) {
    __shared__ __align__(16) float sW[8192];
    __shared__ float sR[64 * 65];
    for (int i = threadIdx.x * 4; i < 8192; i += 1024) {
        *(float4*)&sW[i] = (i < 4096) ? *(const float4*)&Ws[i]
                                      : *(const float4*)&Wv[i - 4096];
    }
    const int c4 = (threadIdx.x & 15) << 2;
    const int rq = threadIdx.x >> 4;
    const int totalRows = 4 * N;
    const int lim = totalRows * 64;
    const int ntiles = (totalRows + 63) >> 6;

    for (int tile = blockIdx.x; tile < ntiles; tile += gridDim.x) {
        const int r0 = tile << 6;
        __syncthreads();
        for (int i = threadIdx.x; i < 4096; i += 256) {
            const int gi = r0 * 64 + i;
            sR[(i >> 6) * 65 + (i & 63)] = (gi < lim) ? out[gi] : 0.f;
        }
        __syncthreads();

        const int rb = rq << 2;
        const int gr = r0 + rb;
        const int o0 = (gr + 0 < N) ? 0 : 4096;
        const int o3 = (gr + 3 < N) ? 0 : 4096;
        float4 a0 = {0,0,0,0}, a1 = {0,0,0,0}, a2 = {0,0,0,0}, a3 = {0,0,0,0};
        const float* rp0 = &sR[(rb + 0) * 65];
        const float* rp1 = &sR[(rb + 1) * 65];
        const float* rp2 = &sR[(rb + 2) * 65];
        const float* rp3 = &sR[(rb + 3) * 65];
        if (o0 == o3) {
            const float* wb = &sW[o0 + c4];
            #pragma unroll 8
            for (int k = 0; k < 64; ++k) {
                const float4 w = *(const float4*)&wb[k * 64];
                const float e0 = rp0[k], e1 = rp1[k], e2 = rp2[k], e3 = rp3[k];
                a0.x += e0 * w.x; a0.y += e0 * w.y; a0.z += e0 * w.z; a0.w += e0 * w.w;
                a1.x += e1 * w.x; a1.y += e1 * w.y; a1.z += e1 * w.z; a1.w += e1 * w.w;
                a2.x += e2 * w.x; a2.y += e2 * w.y; a2.z += e2 * w.z; a2.w += e2 * w.w;
                a3.x += e3 * w.x; a3.y += e3 * w.y; a3.z += e3 * w.z; a3.w += e3 * w.w;
            }
        } else {
            const int o1 = (gr + 1 < N) ? 0 : 4096;
            const int o2 = (gr + 2 < N) ? 0 : 4096;
            #pragma unroll 4
            for (int k = 0; k < 64; ++k) {
                const float4 w0 = *(const float4*)&sW[o0 + k * 64 + c4];
                const float4 w1 = *(const float4*)&sW[o1 + k * 64 + c4];
                const float4 w2 = *(const float4*)&sW[o2 + k * 64 + c4];
                const float4 w3 = *(const float4*)&sW[o3 + k * 64 + c4];
                const float e0 = rp0[k], e1 = rp1[k], e2 = rp2[k], e3 = rp3[k];
                a0.x += e0 * w0.x; a0.y += e0 * w0.y; a0.z += e0 * w0.z; a0.w += e0 * w0.w;
                a1.x += e1 * w1.x; a1.y += e1 * w1.y; a1.z += e1 * w1.z; a1.w += e1 * w1.w;
                a2.x += e2 * w2.x; a2.y += e2 * w2.y; a2.z += e2 * w2.z; a2.w += e2 * w2.w;
                a3.x += e3 * w3.x; a3.y += e3 * w3.y; a3.z += e3 * w3.z; a3.w += e3 * w3.w;
            }
        }
        if (gr + 0 < totalRows) *(float4*)&out[(size_t)(gr + 0) * 64 + c4] = a0;
        if (gr + 1 < totalRows) *(float4*)&out[(size_t)(gr + 1) * 64 + c4] = a1;
        if (gr + 2 < totalRows) *(float4*)&out[(size_t)(gr + 2) * 64 + c4] = a2;
        if (gr + 3 < totalRows) *(float4*)&out[(size_t)(gr + 3) * 64 + c4] = a3;
    }
}

// ---------------------------------------------------------------- full fallback
__global__ __launch_bounds__(512, 1) void edge_k(
    const int* __restrict__ src, const int* __restrict__ dst,
    const float* __restrict__ r_ij, const float* __restrict__ z0g,
    const float* __restrict__ z1g, const float* __restrict__ emb,
    const float* __restrict__ Wenc, const float* __restrict__ benc,
    const float* __restrict__ Wsrc, const float* __restrict__ bsrc,
    const float* __restrict__ Wdst, const float* __restrict__ bdst,
    const float* __restrict__ Wgate, const float* __restrict__ bgate,
    const float* __restrict__ Ws, const float* __restrict__ Wv,
    float* __restrict__ out, int N, int E)
{
    __shared__ float sWsrc[4096];
    __shared__ float sWdst[4096];
    __shared__ float sWg[16384];
    __shared__ float sWs[4096];
    __shared__ float sWv[4096];
    __shared__ float sWe[512];
    __shared__ float sB[64];
    __shared__ float sBg[256];
    __shared__ int sFl[2];

    if (threadIdx.x == 0) {
        const u32* ps = (const u32*)src;
        const u32* pd = (const u32*)dst;
        int s64 = 1, d64 = 1;
        for (int i = 1; i < 128; i += 2) {
            if (ps[i] != 0u) s64 = 0;
            if (pd[i] != 0u) d64 = 0;
        }
        sFl[0] = s64;
        sFl[1] = d64;
    }
    for (int i = threadIdx.x; i < 4096; i += 512) {
        sWsrc[i] = Wsrc[i];
        sWdst[i] = Wdst[i];
        sWs[i] = Ws[i];
        sWv[i] = Wv[i];
    }
    for (int i = threadIdx.x; i < 16384; i += 512) sWg[i] = Wgate[i];
    for (int i = threadIdx.x; i < 512; i += 512) sWe[i] = Wenc[i];
    if (threadIdx.x < 64)
        sB[threadIdx.x] = benc[threadIdx.x] + bsrc[threadIdx.x] + bdst[threadIdx.x];
    if (threadIdx.x < 256) sBg[threadIdx.x] = bgate[threadIdx.x];
    __syncthreads();

    const int wid = threadIdx.x >> 6, lane = threadIdx.x & 63;
    const int i64s = sFl[0], i64d = sFl[1];

    for (int e = blockIdx.x * 8 + wid; e < E; e += gridDim.x * 8) {
        const int s = i64s ? src[2 * e] : src[e];
        const int t = i64d ? dst[2 * e] : dst[e];
        if (s < 0 || s >= N || t < 0 || t >= N) continue;

        const float es = emb[s * 64 + lane];
        const float et = emb[t * 64 + lane];
        float de = sB[lane];
        #pragma unroll 8
        for (int k = 0; k < 64; ++k) {
            de += __shfl(es, k, 64) * sWsrc[(k << 6) + lane];
            de += __shfl(et, k, 64) * sWdst[(k << 6) + lane];
        }
        const float r0 = r_ij[e * 3 + 0];
        const float r1 = r_ij[e * 3 + 1];
        const float r2 = r_ij[e * 3 + 2];
        const float d = sqrtf(r0 * r0 + r1 * r1 + r2 * r2);
        #pragma unroll
        for (int m = 0; m < 8; ++m) {
            const float mu = (2.0f / 7.0f) * (float)m;
            const float tt = (d - mu) * 4.0f;
            de += __expf(-tt * tt) * sWe[m * 64 + lane];
        }

        const float v0 = r0 * 3.5f, v1 = r1 * 3.5f, v2 = r2 * 3.5f;
        const float inv = rsqrtf(1.0f + v0 * v0 + v1 * v1 + v2 * v2);
        const float h0 = v0 * inv, h1 = v1 * inv, h2 = v2 * inv;

        const float z0v = z0g[t * 64 + lane];
        const float za = z1g[t * 192 + lane];
        const float zb = z1g[t * 192 + 64 + lane];
        const float zc = z1g[t * 192 + 128 + lane];
        const float uu = h0 * za + h1 * zb + h2 * zc;

        float g0 = sBg[lane], g1 = sBg[64 + lane], g2 = sBg[128 + lane], g3 = sBg[192 + lane];
        #pragma unroll 8
        for (int k = 0; k < 64; ++k) {
            const float dk = __shfl(de, k, 64);
            const float* w = &sWg[(k << 8) + lane];
            g0 += dk * w[0];
            g1 += dk * w[64];
            g2 += dk * w[128];
            g3 += dk * w[192];
        }

        const float smsg = g0 * z0v + g1 * uu;
        const float vm0 = g2 * za + g3 * h0 * z0v;
        const float vm1 = g2 * zb + g3 * h1 * z0v;
        const float vm2 = g2 * zc + g3 * h2 * z0v;

        float p0 = 0.f, q0 = 0.f, q1 = 0.f, q2 = 0.f;
        #pragma unroll 8
        for (int k = 0; k < 64; ++k) {
            const float sk = __shfl(smsg, k, 64);
            const float a = __shfl(vm0, k, 64);
            const float b = __shfl(vm1, k, 64);
            const float c = __shfl(vm2, k, 64);
            p0 += sk * sWs[(k << 6) + lane];
            const float wv = sWv[(k << 6) + lane];
            q0 += a * wv;
            q1 += b * wv;
            q2 += c * wv;
        }

        atomicAdd(&out[s * 64 + lane], p0);
        const int b1 = N * 64 + s * 192 + lane;
        atomicAdd(&out[b1], q0);
        atomicAdd(&out[b1 + 64], q1);
        atomicAdd(&out[b1 + 128], q2);
    }
}

extern "C" void kernel_launch(void* const* d_in, const int* in_sizes, int n_in,
                              void* d_out, int out_size, void* d_ws, size_t ws_size,
                              hipStream_t stream) {
    const int* src = (const int*)d_in[0];
    const int* dst = (const int*)d_in[1];
    const float* r_ij = (const float*)d_in[2];
    const float* z0g  = (const float*)d_in[3];
    const float* z1g  = (const float*)d_in[4];
    const float* emb  = (const float*)d_in[5];
    const float* Wenc = (const float*)d_in[6];
    const float* benc = (const float*)d_in[7];
    const float* Wsrc = (const float*)d_in[8];
    const float* bsrc = (const float*)d_in[9];
    const float* Wdst = (const float*)d_in[10];
    const float* bdst = (const float*)d_in[11];
    const float* Wgate = (const float*)d_in[12];
    const float* bgate = (const float*)d_in[13];
    const float* Ws = (const float*)d_in[14];
    const float* Wv = (const float*)d_in[15];

    const int N = out_size / 256;                    // out0 N*64 + out1 N*192
    int E = in_sizes[0];
    if (in_sizes[2] / 3 < E) E = in_sizes[2] / 3;    // robustness

    zero_k<<<2048, 256, 0, stream>>>((float*)d_out, out_size);

    float* ws = (float*)d_ws;
    const size_t need = ((size_t)WS_GS + (size_t)N * 512u) * sizeof(float);

    if (ws != nullptr && ws_size >= need) {
        compose_k<<<73, 256, 0, stream>>>(Wsrc, Wdst, Wenc, benc, bsrc, bdst,
                                          Wgate, bgate, ws);
        float* G = ws + WS_GS;
        nodepre3_k<<<256, 512, 0, stream>>>(emb, ws + WS_WSG, G, N);
        edge_ilp2_k<<<2048, 256, 0, stream>>>(src, dst, r_ij, z0g, z1g, G,
                                              ws + WS_WEG, ws + WS_BALL,
                                              (float*)d_out, N, E);
        nodepost3_k<<<2048, 256, 0, stream>>>((float*)d_out, Ws, Wv, N);
    } else {
        edge_k<<<2048, 512, 0, stream>>>(src, dst, r_ij, z0g, z1g, emb, Wenc, benc,
                                         Wsrc, bsrc, Wdst, bdst, Wgate, bgate, Ws, Wv,
                                         (float*)d_out, N, E);
    }
}

// Round 8
// 676.166 us; speedup vs baseline: 1.3179x; 1.1089x over previous
//
#include <hip/hip_runtime.h>

typedef unsigned int u32;
typedef _Float16 h16;
typedef __attribute__((ext_vector_type(4))) _Float16 h4;   // 8 bytes

// ---- workspace layout (float offsets) ----
// Wc = [WsG | WdG] as [64][512], COLUMN-PERMUTED: position p holds original
// column perm(p); perm chosen so G rows come out lane-packed (see compose_k).
#define WS_WSG   0        // 64x512 combined permuted  (32768 floats)
#define WS_WEG   32768    // 8x256 : Wenc @ Wgate   [m][j]  (original order)
#define WS_BALL  34816    // 256   : (benc+bsrc+bdst) @ Wgate + bgate
#define WS_GS    35328    // HG: N x 512 half (lane-packed), then HZ: N x 256 half

// ---------------------------------------------------------------- zero out
__global__ void zero_k(float* p, int n) {
    int i = blockIdx.x * blockDim.x + threadIdx.x;
    int st = gridDim.x * blockDim.x;
    for (; i < n; i += st) p[i] = 0.0f;
}

// ---------------------------------------------------------------- compose weights
// 73 blocks x 256 threads. Thread j computes ORIGINAL column j of WsG/WdG and
// stores it at permuted position p = (j&63)*4 + (j>>6), so that the fp16 G row
// HG[n][lane*4+q] equals original G[n][q*64+lane].
__global__ void compose_k(const float* __restrict__ Wsrc, const float* __restrict__ Wdst,
                          const float* __restrict__ Wenc, const float* __restrict__ benc,
                          const float* __restrict__ bsrc, const float* __restrict__ bdst,
                          const float* __restrict__ Wgate, const float* __restrict__ bgate,
                          float* __restrict__ ws) {
    const int j = threadIdx.x;           // 0..255 (original column)
    const int r = blockIdx.x;            // 0..72
    const int p = ((j & 63) << 2) + (j >> 6);   // permuted position
    if (r < 64) {
        float a = 0.f, b = 0.f;
        for (int c = 0; c < 64; ++c) {
            const float wg = Wgate[c * 256 + j];
            a += Wsrc[r * 64 + c] * wg;
            b += Wdst[r * 64 + c] * wg;
        }
        ws[WS_WSG + r * 512 + p] = a;
        ws[WS_WSG + r * 512 + 256 + p] = b;
    } else if (r < 72) {
        const int m = r - 64;
        float a = 0.f;
        for (int c = 0; c < 64; ++c) a += Wenc[m * 64 + c] * Wgate[c * 256 + j];
        ws[WS_WEG + m * 256 + j] = a;     // original order (edge indexes by q*64+lane)
    } else {
        float a = bgate[j];
        for (int c = 0; c < 64; ++c)
            a += (benc[c] + bsrc[c] + bdst[c]) * Wgate[c * 256 + j];
        ws[WS_BALL + j] = a;              // original order
    }
}

// ---------------------------------------------------------------- node precompute (fp16 out)
// HG[n][0..511] = emb[n][:] @ Wc (permuted cols), stored as half.
// Structure identical to verified round-5 nodepre3; only the store converts.
__global__ __launch_bounds__(512, 1) void nodepre3_k(
    const float* __restrict__ emb, const float* __restrict__ Wc,
    h16* __restrict__ HG, int N) {
    __shared__ __align__(16) float sW[32768];    // 128 KB [k][512]
    __shared__ __align__(16) float sEm[1024];    // 16 node rows
    for (int i = threadIdx.x * 4; i < 32768; i += 2048)
        *(float4*)&sW[i] = *(const float4*)&Wc[i];

    const int c4 = (threadIdx.x & 127) << 2;
    const int g = threadIdx.x >> 7;
    const int lim = N * 64;
    const int ntiles = (N + 15) >> 4;

    for (int tile = blockIdx.x; tile < ntiles; tile += gridDim.x) {
        const int n0 = tile << 4;
        const int base = n0 * 64;
        __syncthreads();
        for (int i = threadIdx.x * 4; i < 1024; i += 2048) {
            const int gi = base + i;
            *(float4*)&sEm[i] = (gi < lim) ? *(const float4*)&emb[gi]
                                           : make_float4(0.f, 0.f, 0.f, 0.f);
        }
        __syncthreads();

        float4 a0 = {0,0,0,0}, a1 = {0,0,0,0}, a2 = {0,0,0,0}, a3 = {0,0,0,0};
        const float* e0p = &sEm[(g * 4 + 0) * 64];
        const float* e1p = &sEm[(g * 4 + 1) * 64];
        const float* e2p = &sEm[(g * 4 + 2) * 64];
        const float* e3p = &sEm[(g * 4 + 3) * 64];
        #pragma unroll 8
        for (int k = 0; k < 64; ++k) {
            const float4 w = *(const float4*)&sW[k * 512 + c4];
            const float e0 = e0p[k], e1 = e1p[k], e2 = e2p[k], e3 = e3p[k];
            a0.x += e0 * w.x; a0.y += e0 * w.y; a0.z += e0 * w.z; a0.w += e0 * w.w;
            a1.x += e1 * w.x; a1.y += e1 * w.y; a1.z += e1 * w.z; a1.w += e1 * w.w;
            a2.x += e2 * w.x; a2.y += e2 * w.y; a2.z += e2 * w.z; a2.w += e2 * w.w;
            a3.x += e3 * w.x; a3.y += e3 * w.y; a3.z += e3 * w.z; a3.w += e3 * w.w;
        }
        const int nb = n0 + g * 4;
        const h4 h0 = { (h16)a0.x, (h16)a0.y, (h16)a0.z, (h16)a0.w };
        const h4 h1 = { (h16)a1.x, (h16)a1.y, (h16)a1.z, (h16)a1.w };
        const h4 h2 = { (h16)a2.x, (h16)a2.y, (h16)a2.z, (h16)a2.w };
        const h4 h3 = { (h16)a3.x, (h16)a3.y, (h16)a3.z, (h16)a3.w };
        if (nb + 0 < N) *(h4*)&HG[(size_t)(nb + 0) * 512 + c4] = h0;
        if (nb + 1 < N) *(h4*)&HG[(size_t)(nb + 1) * 512 + c4] = h1;
        if (nb + 2 < N) *(h4*)&HG[(size_t)(nb + 2) * 512 + c4] = h2;
        if (nb + 3 < N) *(h4*)&HG[(size_t)(nb + 3) * 512 + c4] = h3;
    }
}

// ---------------------------------------------------------------- z pack (fp16)
// HZ[n][l*4+{0,1,2,3}] = { z1[n][0][l], z1[n][1][l], z1[n][2][l], z0[n][l] }
__global__ void hz_k(const float* __restrict__ z0g, const float* __restrict__ z1g,
                     h16* __restrict__ HZ, int N) {
    const int tot = N * 64;
    for (int idx = blockIdx.x * blockDim.x + threadIdx.x; idx < tot;
         idx += gridDim.x * blockDim.x) {
        const int n = idx >> 6, l = idx & 63;
        const h4 v = { (h16)z1g[n * 192 + l], (h16)z1g[n * 192 + 64 + l],
                       (h16)z1g[n * 192 + 128 + l], (h16)z0g[n * 64 + l] };
        *(h4*)&HZ[(size_t)n * 256 + (l << 2)] = v;
    }
}

// ---------------------------------------------------------------- edge kernel (fp16 gathers)
// Round-1 proven strided traversal; per edge per lane only THREE 8B gathers
// (HG-s, HG-d, HZ-t). Math in fp32; atomics unchanged.
__global__ __launch_bounds__(256, 8) void edge_h16_k(
    const int* __restrict__ src, const int* __restrict__ dst,
    const float* __restrict__ r_ij, const h16* __restrict__ HG,
    const h16* __restrict__ HZ, const float* __restrict__ WeG,
    const float* __restrict__ ball, float* __restrict__ out, int N, int E) {
    __shared__ float sWe[2048];   // 8 KB
    __shared__ float sBall[256];  // 1 KB
    __shared__ int sFl[2];

    if (threadIdx.x == 0) {
        const u32* ps = (const u32*)src;
        const u32* pd = (const u32*)dst;
        int s64 = 1, d64 = 1;
        for (int i = 1; i < 128; i += 2) {
            if (ps[i] != 0u) s64 = 0;
            if (pd[i] != 0u) d64 = 0;
        }
        sFl[0] = s64;
        sFl[1] = d64;
    }
    for (int i = threadIdx.x; i < 2048; i += 256) sWe[i] = WeG[i];
    sBall[threadIdx.x] = ball[threadIdx.x];
    __syncthreads();

    const int wid = threadIdx.x >> 6, lane = threadIdx.x & 63;
    const int i64s = sFl[0], i64d = sFl[1];

    const float bl0 = sBall[lane], bl1 = sBall[64 + lane];
    const float bl2 = sBall[128 + lane], bl3 = sBall[192 + lane];

    for (int e = blockIdx.x * 4 + wid; e < E; e += gridDim.x * 4) {
        const int s = i64s ? src[2 * e] : src[e];
        const int t = i64d ? dst[2 * e] : dst[e];
        if (s < 0 || s >= N || t < 0 || t >= N) continue;

        // three 8B gathers per lane
        const h4 gsv = *(const h4*)&HG[(size_t)s * 512 + (lane << 2)];
        const h4 gdv = *(const h4*)&HG[(size_t)t * 512 + 256 + (lane << 2)];
        const h4 zv  = *(const h4*)&HZ[(size_t)t * 256 + (lane << 2)];
        const float r0 = r_ij[e * 3 + 0];
        const float r1 = r_ij[e * 3 + 1];
        const float r2 = r_ij[e * 3 + 2];

        float g0 = (float)gsv.x + (float)gdv.x + bl0;
        float g1 = (float)gsv.y + (float)gdv.y + bl1;
        float g2 = (float)gsv.z + (float)gdv.z + bl2;
        float g3 = (float)gsv.w + (float)gdv.w + bl3;
        const float za = (float)zv.x, zb = (float)zv.y, zc = (float)zv.z;
        const float z0v = (float)zv.w;

        const float d = sqrtf(r0 * r0 + r1 * r1 + r2 * r2);
        #pragma unroll
        for (int m = 0; m < 8; ++m) {
            const float mu = 0.28571428571f * (float)m;   // linspace(0, 2, 8)
            const float tt = (d - mu) * 4.0f;             // / sigma, sigma = 0.25
            const float rm = __expf(-tt * tt);
            const float* wq = &sWe[(m << 8) + lane];
            g0 += rm * wq[0];
            g1 += rm * wq[64];
            g2 += rm * wq[128];
            g3 += rm * wq[192];
        }

        // r_hat = v/sqrt(1+|v|^2), v = r_ij*3.5
        const float v0 = r0 * 3.5f, v1 = r1 * 3.5f, v2 = r2 * 3.5f;
        const float inv = rsqrtf(1.0f + v0 * v0 + v1 * v1 + v2 * v2);
        const float h0 = v0 * inv, h1 = v1 * inv, h2 = v2 * inv;
        const float uu = h0 * za + h1 * zb + h2 * zc;     // r_hat . z1_j

        const float smsg = g0 * z0v + g1 * uu;
        const float vm0 = g2 * za + g3 * h0 * z0v;
        const float vm1 = g2 * zb + g3 * h1 * z0v;
        const float vm2 = g2 * zc + g3 * h2 * z0v;

        atomicAdd(&out[s * 64 + lane], smsg);
        const int bo = N * 64 + s * 192 + lane;
        atomicAdd(&out[bo], vm0);
        atomicAdd(&out[bo + 64], vm1);
        atomicAdd(&out[bo + 128], vm2);
    }
}

// ---------------------------------------------------------------- node epilogue v3
// (verified round 5) out = (4N)x64 row-major; rows<N use Ws else Wv. In-place.
__global__ __launch_bounds__(256, 3) void nodepost3_k(
    float* __restrict__ out, const float* __restrict__ Ws,
    const float* __restrict__ Wv, int N) {
    __shared__ __align__(16) float sW[8192];
    __shared__ float sR[64 * 65];
    for (int i = threadIdx.x * 4; i < 8192; i += 1024) {
        *(float4*)&sW[i] = (i < 4096) ? *(const float4*)&Ws[i]
                                      : *(const float4*)&Wv[i - 4096];
    }
    const int c4 = (threadIdx.x & 15) << 2;
    const int rq = threadIdx.x >> 4;
    const int totalRows = 4 * N;
    const int lim = totalRows * 64;
    const int ntiles = (totalRows + 63) >> 6;

    for (int tile = blockIdx.x; tile < ntiles; tile += gridDim.x) {
        const int r0 = tile << 6;
        __syncthreads();
        for (int i = threadIdx.x; i < 4096; i += 256) {
            const int gi = r0 * 64 + i;
            sR[(i >> 6) * 65 + (i & 63)] = (gi < lim) ? out[gi] : 0.f;
        }
        __syncthreads();

        const int rb = rq << 2;
        const int gr = r0 + rb;
        const int o0 = (gr + 0 < N) ? 0 : 4096;
        const int o3 = (gr + 3 < N) ? 0 : 4096;
        float4 a0 = {0,0,0,0}, a1 = {0,0,0,0}, a2 = {0,0,0,0}, a3 = {0,0,0,0};
        const float* rp0 = &sR[(rb + 0) * 65];
        const float* rp1 = &sR[(rb + 1) * 65];
        const float* rp2 = &sR[(rb + 2) * 65];
        const float* rp3 = &sR[(rb + 3) * 65];
        if (o0 == o3) {
            const float* wb = &sW[o0 + c4];
            #pragma unroll 8
            for (int k = 0; k < 64; ++k) {
                const float4 w = *(const float4*)&wb[k * 64];
                const float e0 = rp0[k], e1 = rp1[k], e2 = rp2[k], e3 = rp3[k];
                a0.x += e0 * w.x; a0.y += e0 * w.y; a0.z += e0 * w.z; a0.w += e0 * w.w;
                a1.x += e1 * w.x; a1.y += e1 * w.y; a1.z += e1 * w.z; a1.w += e1 * w.w;
                a2.x += e2 * w.x; a2.y += e2 * w.y; a2.z += e2 * w.z; a2.w += e2 * w.w;
                a3.x += e3 * w.x; a3.y += e3 * w.y; a3.z += e3 * w.z; a3.w += e3 * w.w;
            }
        } else {
            const int o1 = (gr + 1 < N) ? 0 : 4096;
            const int o2 = (gr + 2 < N) ? 0 : 4096;
            #pragma unroll 4
            for (int k = 0; k < 64; ++k) {
                const float4 w0 = *(const float4*)&sW[o0 + k * 64 + c4];
                const float4 w1 = *(const float4*)&sW[o1 + k * 64 + c4];
                const float4 w2 = *(const float4*)&sW[o2 + k * 64 + c4];
                const float4 w3 = *(const float4*)&sW[o3 + k * 64 + c4];
                const float e0 = rp0[k], e1 = rp1[k], e2 = rp2[k], e3 = rp3[k];
                a0.x += e0 * w0.x; a0.y += e0 * w0.y; a0.z += e0 * w0.z; a0.w += e0 * w0.w;
                a1.x += e1 * w1.x; a1.y += e1 * w1.y; a1.z += e1 * w1.z; a1.w += e1 * w1.w;
                a2.x += e2 * w2.x; a2.y += e2 * w2.y; a2.z += e2 * w2.z; a2.w += e2 * w2.w;
                a3.x += e3 * w3.x; a3.y += e3 * w3.y; a3.z += e3 * w3.z; a3.w += e3 * w3.w;
            }
        }
        if (gr + 0 < totalRows) *(float4*)&out[(size_t)(gr + 0) * 64 + c4] = a0;
        if (gr + 1 < totalRows) *(float4*)&out[(size_t)(gr + 1) * 64 + c4] = a1;
        if (gr + 2 < totalRows) *(float4*)&out[(size_t)(gr + 2) * 64 + c4] = a2;
        if (gr + 3 < totalRows) *(float4*)&out[(size_t)(gr + 3) * 64 + c4] = a3;
    }
}

// ---------------------------------------------------------------- full fallback
__global__ __launch_bounds__(512, 1) void edge_k(
    const int* __restrict__ src, const int* __restrict__ dst,
    const float* __restrict__ r_ij, const float* __restrict__ z0g,
    const float* __restrict__ z1g, const float* __restrict__ emb,
    const float* __restrict__ Wenc, const float* __restrict__ benc,
    const float* __restrict__ Wsrc, const float* __restrict__ bsrc,
    const float* __restrict__ Wdst, const float* __restrict__ bdst,
    const float* __restrict__ Wgate, const float* __restrict__ bgate,
    const float* __restrict__ Ws, const float* __restrict__ Wv,
    float* __restrict__ out, int N, int E)
{
    __shared__ float sWsrc[4096];
    __shared__ float sWdst[4096];
    __shared__ float sWg[16384];
    __shared__ float sWs[4096];
    __shared__ float sWv[4096];
    __shared__ float sWe[512];
    __shared__ float sB[64];
    __shared__ float sBg[256];
    __shared__ int sFl[2];

    if (threadIdx.x == 0) {
        const u32* ps = (const u32*)src;
        const u32* pd = (const u32*)dst;
        int s64 = 1, d64 = 1;
        for (int i = 1; i < 128; i += 2) {
            if (ps[i] != 0u) s64 = 0;
            if (pd[i] != 0u) d64 = 0;
        }
        sFl[0] = s64;
        sFl[1] = d64;
    }
    for (int i = threadIdx.x; i < 4096; i += 512) {
        sWsrc[i] = Wsrc[i];
        sWdst[i] = Wdst[i];
        sWs[i] = Ws[i];
        sWv[i] = Wv[i];
    }
    for (int i = threadIdx.x; i < 16384; i += 512) sWg[i] = Wgate[i];
    for (int i = threadIdx.x; i < 512; i += 512) sWe[i] = Wenc[i];
    if (threadIdx.x < 64)
        sB[threadIdx.x] = benc[threadIdx.x] + bsrc[threadIdx.x] + bdst[threadIdx.x];
    if (threadIdx.x < 256) sBg[threadIdx.x] = bgate[threadIdx.x];
    __syncthreads();

    const int wid = threadIdx.x >> 6, lane = threadIdx.x & 63;
    const int i64s = sFl[0], i64d = sFl[1];

    for (int e = blockIdx.x * 8 + wid; e < E; e += gridDim.x * 8) {
        const int s = i64s ? src[2 * e] : src[e];
        const int t = i64d ? dst[2 * e] : dst[e];
        if (s < 0 || s >= N || t < 0 || t >= N) continue;

        const float es = emb[s * 64 + lane];
        const float et = emb[t * 64 + lane];
        float de = sB[lane];
        #pragma unroll 8
        for (int k = 0; k < 64; ++k) {
            de += __shfl(es, k, 64) * sWsrc[(k << 6) + lane];
            de += __shfl(et, k, 64) * sWdst[(k << 6) + lane];
        }
        const float r0 = r_ij[e * 3 + 0];
        const float r1 = r_ij[e * 3 + 1];
        const float r2 = r_ij[e * 3 + 2];
        const float d = sqrtf(r0 * r0 + r1 * r1 + r2 * r2);
        #pragma unroll
        for (int m = 0; m < 8; ++m) {
            const float mu = (2.0f / 7.0f) * (float)m;
            const float tt = (d - mu) * 4.0f;
            de += __expf(-tt * tt) * sWe[m * 64 + lane];
        }

        const float v0 = r0 * 3.5f, v1 = r1 * 3.5f, v2 = r2 * 3.5f;
        const float inv = rsqrtf(1.0f + v0 * v0 + v1 * v1 + v2 * v2);
        const float h0 = v0 * inv, h1 = v1 * inv, h2 = v2 * inv;

        const float z0v = z0g[t * 64 + lane];
        const float za = z1g[t * 192 + lane];
        const float zb = z1g[t * 192 + 64 + lane];
        const float zc = z1g[t * 192 + 128 + lane];
        const float uu = h0 * za + h1 * zb + h2 * zc;

        float g0 = sBg[lane], g1 = sBg[64 + lane], g2 = sBg[128 + lane], g3 = sBg[192 + lane];
        #pragma unroll 8
        for (int k = 0; k < 64; ++k) {
            const float dk = __shfl(de, k, 64);
            const float* w = &sWg[(k << 8) + lane];
            g0 += dk * w[0];
            g1 += dk * w[64];
            g2 += dk * w[128];
            g3 += dk * w[192];
        }

        const float smsg = g0 * z0v + g1 * uu;
        const float vm0 = g2 * za + g3 * h0 * z0v;
        const float vm1 = g2 * zb + g3 * h1 * z0v;
        const float vm2 = g2 * zc + g3 * h2 * z0v;

        float p0 = 0.f, q0 = 0.f, q1 = 0.f, q2 = 0.f;
        #pragma unroll 8
        for (int k = 0; k < 64; ++k) {
            const float sk = __shfl(smsg, k, 64);
            const float a = __shfl(vm0, k, 64);
            const float b = __shfl(vm1, k, 64);
            const float c = __shfl(vm2, k, 64);
            p0 += sk * sWs[(k << 6) + lane];
            const float wv = sWv[(k << 6) + lane];
            q0 += a * wv;
            q1 += b * wv;
            q2 += c * wv;
        }

        atomicAdd(&out[s * 64 + lane], p0);
        const int b1 = N * 64 + s * 192 + lane;
        atomicAdd(&out[b1], q0);
        atomicAdd(&out[b1 + 64], q1);
        atomicAdd(&out[b1 + 128], q2);
    }
}

extern "C" void kernel_launch(void* const* d_in, const int* in_sizes, int n_in,
                              void* d_out, int out_size, void* d_ws, size_t ws_size,
                              hipStream_t stream) {
    const int* src = (const int*)d_in[0];
    const int* dst = (const int*)d_in[1];
    const float* r_ij = (const float*)d_in[2];
    const float* z0g  = (const float*)d_in[3];
    const float* z1g  = (const float*)d_in[4];
    const float* emb  = (const float*)d_in[5];
    const float* Wenc = (const float*)d_in[6];
    const float* benc = (const float*)d_in[7];
    const float* Wsrc = (const float*)d_in[8];
    const float* bsrc = (const float*)d_in[9];
    const float* Wdst = (const float*)d_in[10];
    const float* bdst = (const float*)d_in[11];
    const float* Wgate = (const float*)d_in[12];
    const float* bgate = (const float*)d_in[13];
    const float* Ws = (const float*)d_in[14];
    const float* Wv = (const float*)d_in[15];

    const int N = out_size / 256;                    // out0 N*64 + out1 N*192
    int E = in_sizes[0];
    if (in_sizes[2] / 3 < E) E = in_sizes[2] / 3;    // robustness

    zero_k<<<2048, 256, 0, stream>>>((float*)d_out, out_size);

    float* ws = (float*)d_ws;
    // HG: N*512 half = N*256 float slots; HZ: N*256 half = N*128 float slots
    const size_t need = ((size_t)WS_GS + (size_t)N * 384u + 16u) * sizeof(float);

    if (ws != nullptr && ws_size >= need) {
        compose_k<<<73, 256, 0, stream>>>(Wsrc, Wdst, Wenc, benc, bsrc, bdst,
                                          Wgate, bgate, ws);
        h16* HG = (h16*)(ws + WS_GS);
        h16* HZ = HG + (size_t)N * 512;
        nodepre3_k<<<256, 512, 0, stream>>>(emb, ws + WS_WSG, HG, N);
        hz_k<<<1024, 256, 0, stream>>>(z0g, z1g, HZ, N);
        edge_h16_k<<<2048, 256, 0, stream>>>(src, dst, r_ij, HG, HZ,
                                             ws + WS_WEG, ws + WS_BALL,
                                             (float*)d_out, N, E);
        nodepost3_k<<<2048, 256, 0, stream>>>((float*)d_out, Ws, Wv, N);
    } else {
        edge_k<<<2048, 512, 0, stream>>>(src, dst, r_ij, z0g, z1g, emb, Wenc, benc,
                                         Wsrc, bsrc, Wdst, bdst, Wgate, bgate, Ws, Wv,
                                         (float*)d_out, N, E);
    }
}

// Round 10
// 673.111 us; speedup vs baseline: 1.3239x; 1.0045x over previous
//
#include <hip/hip_runtime.h>

typedef unsigned int u32;
typedef _Float16 h16;
typedef __attribute__((ext_vector_type(2))) _Float16 h2;   // 4 bytes
typedef __attribute__((ext_vector_type(4))) _Float16 h4;   // 8 bytes

// ---- workspace layout (float offsets) ----
// Wc = [WsG | WdG] as [64][512], COLUMN-PERMUTED: position p holds original
// column perm(p); perm chosen so G rows come out lane-packed (see compose_k).
#define WS_WSG   0        // 64x512 combined permuted  (32768 floats)
#define WS_WEG   32768    // 8x256 : Wenc @ Wgate   [m][j]  (original order)
#define WS_BALL  34816    // 256   : (benc+bsrc+bdst) @ Wgate + bgate
#define WS_GS    35328    // HG: Nx512 half | HZ: Nx256 half | ACC: Nx256 half

// packed fp16 atomic add (device-scope via sc1; no HIP overload exists on ROCm 7.2)
__device__ __forceinline__ void pk_add(h16* addr, float lo, float hi) {
    union { h2 h; u32 u; } cv;
    cv.h = (h2){ (h16)lo, (h16)hi };
    asm volatile("global_atomic_pk_add_f16 %0, %1, off sc1"
                 :: "v"(addr), "v"(cv.u) : "memory");
}

// ---------------------------------------------------------------- zero out
__global__ void zero_k(float* p, int n) {
    int i = blockIdx.x * blockDim.x + threadIdx.x;
    int st = gridDim.x * blockDim.x;
    for (; i < n; i += st) p[i] = 0.0f;
}

// ---------------------------------------------------------------- compose weights
// 73 blocks x 256 threads. Thread j computes ORIGINAL column j of WsG/WdG and
// stores it at permuted position p = (j&63)*4 + (j>>6), so that the fp16 G row
// HG[n][lane*4+q] equals original G[n][q*64+lane].
__global__ void compose_k(const float* __restrict__ Wsrc, const float* __restrict__ Wdst,
                          const float* __restrict__ Wenc, const float* __restrict__ benc,
                          const float* __restrict__ bsrc, const float* __restrict__ bdst,
                          const float* __restrict__ Wgate, const float* __restrict__ bgate,
                          float* __restrict__ ws) {
    const int j = threadIdx.x;           // 0..255 (original column)
    const int r = blockIdx.x;            // 0..72
    const int p = ((j & 63) << 2) + (j >> 6);   // permuted position
    if (r < 64) {
        float a = 0.f, b = 0.f;
        for (int c = 0; c < 64; ++c) {
            const float wg = Wgate[c * 256 + j];
            a += Wsrc[r * 64 + c] * wg;
            b += Wdst[r * 64 + c] * wg;
        }
        ws[WS_WSG + r * 512 + p] = a;
        ws[WS_WSG + r * 512 + 256 + p] = b;
    } else if (r < 72) {
        const int m = r - 64;
        float a = 0.f;
        for (int c = 0; c < 64; ++c) a += Wenc[m * 64 + c] * Wgate[c * 256 + j];
        ws[WS_WEG + m * 256 + j] = a;     // original order
    } else {
        float a = bgate[j];
        for (int c = 0; c < 64; ++c)
            a += (benc[c] + bsrc[c] + bdst[c]) * Wgate[c * 256 + j];
        ws[WS_BALL + j] = a;              // original order
    }
}

// ---------------------------------------------------------------- node precompute (fp16 out)
// (verified rounds 5/8) HG[n][:] = emb[n][:] @ Wc (permuted cols), half out.
__global__ __launch_bounds__(512, 1) void nodepre3_k(
    const float* __restrict__ emb, const float* __restrict__ Wc,
    h16* __restrict__ HG, int N) {
    __shared__ __align__(16) float sW[32768];    // 128 KB [k][512]
    __shared__ __align__(16) float sEm[1024];    // 16 node rows
    for (int i = threadIdx.x * 4; i < 32768; i += 2048)
        *(float4*)&sW[i] = *(const float4*)&Wc[i];

    const int c4 = (threadIdx.x & 127) << 2;
    const int g = threadIdx.x >> 7;
    const int lim = N * 64;
    const int ntiles = (N + 15) >> 4;

    for (int tile = blockIdx.x; tile < ntiles; tile += gridDim.x) {
        const int n0 = tile << 4;
        const int base = n0 * 64;
        __syncthreads();
        for (int i = threadIdx.x * 4; i < 1024; i += 2048) {
            const int gi = base + i;
            *(float4*)&sEm[i] = (gi < lim) ? *(const float4*)&emb[gi]
                                           : make_float4(0.f, 0.f, 0.f, 0.f);
        }
        __syncthreads();

        float4 a0 = {0,0,0,0}, a1 = {0,0,0,0}, a2 = {0,0,0,0}, a3 = {0,0,0,0};
        const float* e0p = &sEm[(g * 4 + 0) * 64];
        const float* e1p = &sEm[(g * 4 + 1) * 64];
        const float* e2p = &sEm[(g * 4 + 2) * 64];
        const float* e3p = &sEm[(g * 4 + 3) * 64];
        #pragma unroll 8
        for (int k = 0; k < 64; ++k) {
            const float4 w = *(const float4*)&sW[k * 512 + c4];
            const float e0 = e0p[k], e1 = e1p[k], e2 = e2p[k], e3 = e3p[k];
            a0.x += e0 * w.x; a0.y += e0 * w.y; a0.z += e0 * w.z; a0.w += e0 * w.w;
            a1.x += e1 * w.x; a1.y += e1 * w.y; a1.z += e1 * w.z; a1.w += e1 * w.w;
            a2.x += e2 * w.x; a2.y += e2 * w.y; a2.z += e2 * w.z; a2.w += e2 * w.w;
            a3.x += e3 * w.x; a3.y += e3 * w.y; a3.z += e3 * w.z; a3.w += e3 * w.w;
        }
        const int nb = n0 + g * 4;
        const h4 h0 = { (h16)a0.x, (h16)a0.y, (h16)a0.z, (h16)a0.w };
        const h4 h1 = { (h16)a1.x, (h16)a1.y, (h16)a1.z, (h16)a1.w };
        const h4 h2v = { (h16)a2.x, (h16)a2.y, (h16)a2.z, (h16)a2.w };
        const h4 h3 = { (h16)a3.x, (h16)a3.y, (h16)a3.z, (h16)a3.w };
        if (nb + 0 < N) *(h4*)&HG[(size_t)(nb + 0) * 512 + c4] = h0;
        if (nb + 1 < N) *(h4*)&HG[(size_t)(nb + 1) * 512 + c4] = h1;
        if (nb + 2 < N) *(h4*)&HG[(size_t)(nb + 2) * 512 + c4] = h2v;
        if (nb + 3 < N) *(h4*)&HG[(size_t)(nb + 3) * 512 + c4] = h3;
    }
}

// ---------------------------------------------------------------- z pack (fp16)
// HZ[n][l*4+{0,1,2,3}] = { z1[n][0][l], z1[n][1][l], z1[n][2][l], z0[n][l] }
__global__ void hz_k(const float* __restrict__ z0g, const float* __restrict__ z1g,
                     h16* __restrict__ HZ, int N) {
    const int tot = N * 64;
    for (int idx = blockIdx.x * blockDim.x + threadIdx.x; idx < tot;
         idx += gridDim.x * blockDim.x) {
        const int n = idx >> 6, l = idx & 63;
        const h4 v = { (h16)z1g[n * 192 + l], (h16)z1g[n * 192 + 64 + l],
                       (h16)z1g[n * 192 + 128 + l], (h16)z0g[n * 64 + l] };
        *(h4*)&HZ[(size_t)n * 256 + (l << 2)] = v;
    }
}

// ---------------------------------------------------------------- edge kernel (pk16 atomics)
// Round-1 proven strided traversal; three 8B gathers per lane; scatter via
// TWO packed-half2 atomics per edge per lane into ACC (lane-interleaved
// {S,V0,V1,V2}), halving atomic op count and atomic traffic.
__global__ __launch_bounds__(256, 8) void edge_pk_k(
    const int* __restrict__ src, const int* __restrict__ dst,
    const float* __restrict__ r_ij, const h16* __restrict__ HG,
    const h16* __restrict__ HZ, const float* __restrict__ WeG,
    const float* __restrict__ ball, h16* __restrict__ ACC, int N, int E) {
    __shared__ float sWe[2048];   // 8 KB
    __shared__ float sBall[256];  // 1 KB
    __shared__ int sFl[2];

    if (threadIdx.x == 0) {
        const u32* ps = (const u32*)src;
        const u32* pd = (const u32*)dst;
        int s64 = 1, d64 = 1;
        for (int i = 1; i < 128; i += 2) {
            if (ps[i] != 0u) s64 = 0;
            if (pd[i] != 0u) d64 = 0;
        }
        sFl[0] = s64;
        sFl[1] = d64;
    }
    for (int i = threadIdx.x; i < 2048; i += 256) sWe[i] = WeG[i];
    sBall[threadIdx.x] = ball[threadIdx.x];
    __syncthreads();

    const int wid = threadIdx.x >> 6, lane = threadIdx.x & 63;
    const int i64s = sFl[0], i64d = sFl[1];

    const float bl0 = sBall[lane], bl1 = sBall[64 + lane];
    const float bl2 = sBall[128 + lane], bl3 = sBall[192 + lane];

    for (int e = blockIdx.x * 4 + wid; e < E; e += gridDim.x * 4) {
        const int s = i64s ? src[2 * e] : src[e];
        const int t = i64d ? dst[2 * e] : dst[e];
        if (s < 0 || s >= N || t < 0 || t >= N) continue;

        // three 8B gathers per lane
        const h4 gsv = *(const h4*)&HG[(size_t)s * 512 + (lane << 2)];
        const h4 gdv = *(const h4*)&HG[(size_t)t * 512 + 256 + (lane << 2)];
        const h4 zv  = *(const h4*)&HZ[(size_t)t * 256 + (lane << 2)];
        const float r0 = r_ij[e * 3 + 0];
        const float r1 = r_ij[e * 3 + 1];
        const float r2 = r_ij[e * 3 + 2];

        float g0 = (float)gsv.x + (float)gdv.x + bl0;
        float g1 = (float)gsv.y + (float)gdv.y + bl1;
        float g2 = (float)gsv.z + (float)gdv.z + bl2;
        float g3 = (float)gsv.w + (float)gdv.w + bl3;
        const float za = (float)zv.x, zb = (float)zv.y, zc = (float)zv.z;
        const float z0v = (float)zv.w;

        const float d = sqrtf(r0 * r0 + r1 * r1 + r2 * r2);
        #pragma unroll
        for (int m = 0; m < 8; ++m) {
            const float mu = 0.28571428571f * (float)m;   // linspace(0, 2, 8)
            const float tt = (d - mu) * 4.0f;             // / sigma, sigma = 0.25
            const float rm = __expf(-tt * tt);
            const float* wq = &sWe[(m << 8) + lane];
            g0 += rm * wq[0];
            g1 += rm * wq[64];
            g2 += rm * wq[128];
            g3 += rm * wq[192];
        }

        // r_hat = v/sqrt(1+|v|^2), v = r_ij*3.5
        const float v0 = r0 * 3.5f, v1 = r1 * 3.5f, v2 = r2 * 3.5f;
        const float inv = rsqrtf(1.0f + v0 * v0 + v1 * v1 + v2 * v2);
        const float h0 = v0 * inv, h1 = v1 * inv, h2 = v2 * inv;
        const float uu = h0 * za + h1 * zb + h2 * zc;     // r_hat . z1_j

        const float smsg = g0 * z0v + g1 * uu;
        const float vm0 = g2 * za + g3 * h0 * z0v;
        const float vm1 = g2 * zb + g3 * h1 * z0v;
        const float vm2 = g2 * zc + g3 * h2 * z0v;

        // two packed-half2 atomics: ACC[s][lane*4 + {0,1,2,3}] = {S,V0,V1,V2}
        h16* ap = &ACC[(size_t)s * 256 + (lane << 2)];
        pk_add(ap,     smsg, vm0);
        pk_add(ap + 2, vm1,  vm2);
    }
}

// ---------------------------------------------------------------- node epilogue v4
// Reads fp16 ACC (lane-interleaved), de-interleaves into LDS as 64 virtual
// rows [part*16 + node_local][64], applies Ws (part 0) / Wv (parts 1-3),
// writes out0/out1 fully (no pre-zero of out needed).
__global__ __launch_bounds__(256, 3) void nodepost4_k(
    const h16* __restrict__ ACC, float* __restrict__ out,
    const float* __restrict__ Ws, const float* __restrict__ Wv, int N) {
    __shared__ __align__(16) float sW[8192];     // [0..4095]=Ws, [4096..]=Wv
    __shared__ float sR[64 * 65];                // 64 virtual rows, pad 65
    for (int i = threadIdx.x * 4; i < 8192; i += 1024) {
        *(float4*)&sW[i] = (i < 4096) ? *(const float4*)&Ws[i]
                                      : *(const float4*)&Wv[i - 4096];
    }
    const int c4 = (threadIdx.x & 15) << 2;      // col offset 0..60
    const int rq = threadIdx.x >> 4;             // 0..15 -> rows rq*4..+3
    const int lim = N * 256;
    const int ntiles = (N + 15) >> 4;

    for (int tile = blockIdx.x; tile < ntiles; tile += gridDim.x) {
        const int n0 = tile << 4;
        const int base = n0 * 256;
        __syncthreads();
        // stage + de-interleave: h4 at (nl, k) = {S,V0,V1,V2} of column k
        for (int i = threadIdx.x * 4; i < 4096; i += 1024) {
            const int nl = i >> 8;               // node local 0..15
            const int k = (i & 255) >> 2;        // column 0..63
            h4 v = { (h16)0.f, (h16)0.f, (h16)0.f, (h16)0.f };
            if (base + i < lim) v = *(const h4*)&ACC[base + i];
            sR[(nl) * 65 + k] = (float)v.x;             // part 0 rows 0..15
            sR[(16 + nl) * 65 + k] = (float)v.y;        // part 1 rows 16..31
            sR[(32 + nl) * 65 + k] = (float)v.z;        // part 2
            sR[(48 + nl) * 65 + k] = (float)v.w;        // part 3
        }
        __syncthreads();

        const int rb = rq << 2;                  // virtual row base (uniform part)
        const int part = rb >> 4;                // 0..3 (same for all 4 rows)
        const float* wb = &sW[(part == 0 ? 0 : 4096) + c4];
        float4 a0 = {0,0,0,0}, a1 = {0,0,0,0}, a2 = {0,0,0,0}, a3 = {0,0,0,0};
        const float* rp0 = &sR[(rb + 0) * 65];
        const float* rp1 = &sR[(rb + 1) * 65];
        const float* rp2 = &sR[(rb + 2) * 65];
        const float* rp3 = &sR[(rb + 3) * 65];
        #pragma unroll 8
        for (int k = 0; k < 64; ++k) {
            const float4 w = *(const float4*)&wb[k * 64];
            const float e0 = rp0[k], e1 = rp1[k], e2 = rp2[k], e3 = rp3[k];
            a0.x += e0 * w.x; a0.y += e0 * w.y; a0.z += e0 * w.z; a0.w += e0 * w.w;
            a1.x += e1 * w.x; a1.y += e1 * w.y; a1.z += e1 * w.z; a1.w += e1 * w.w;
            a2.x += e2 * w.x; a2.y += e2 * w.y; a2.z += e2 * w.z; a2.w += e2 * w.w;
            a3.x += e3 * w.x; a3.y += e3 * w.y; a3.z += e3 * w.z; a3.w += e3 * w.w;
        }
        // rows rb+i are nodes n0 + ((rb+i)&15), all same part
        #pragma unroll
        for (int i = 0; i < 4; ++i) {
            const int n = n0 + ((rb + i) & 15);
            if (n >= N) continue;
            const float4 av = (i == 0) ? a0 : (i == 1) ? a1 : (i == 2) ? a2 : a3;
            if (part == 0)
                *(float4*)&out[(size_t)n * 64 + c4] = av;
            else
                *(float4*)&out[(size_t)N * 64 + (size_t)n * 192 + (part - 1) * 64 + c4] = av;
        }
    }
}

// ---------------------------------------------------------------- full fallback
__global__ __launch_bounds__(512, 1) void edge_k(
    const int* __restrict__ src, const int* __restrict__ dst,
    const float* __restrict__ r_ij, const float* __restrict__ z0g,
    const float* __restrict__ z1g, const float* __restrict__ emb,
    const float* __restrict__ Wenc, const float* __restrict__ benc,
    const float* __restrict__ Wsrc, const float* __restrict__ bsrc,
    const float* __restrict__ Wdst, const float* __restrict__ bdst,
    const float* __restrict__ Wgate, const float* __restrict__ bgate,
    const float* __restrict__ Ws, const float* __restrict__ Wv,
    float* __restrict__ out, int N, int E)
{
    __shared__ float sWsrc[4096];
    __shared__ float sWdst[4096];
    __shared__ float sWg[16384];
    __shared__ float sWs[4096];
    __shared__ float sWv[4096];
    __shared__ float sWe[512];
    __shared__ float sB[64];
    __shared__ float sBg[256];
    __shared__ int sFl[2];

    if (threadIdx.x == 0) {
        const u32* ps = (const u32*)src;
        const u32* pd = (const u32*)dst;
        int s64 = 1, d64 = 1;
        for (int i = 1; i < 128; i += 2) {
            if (ps[i] != 0u) s64 = 0;
            if (pd[i] != 0u) d64 = 0;
        }
        sFl[0] = s64;
        sFl[1] = d64;
    }
    for (int i = threadIdx.x; i < 4096; i += 512) {
        sWsrc[i] = Wsrc[i];
        sWdst[i] = Wdst[i];
        sWs[i] = Ws[i];
        sWv[i] = Wv[i];
    }
    for (int i = threadIdx.x; i < 16384; i += 512) sWg[i] = Wgate[i];
    for (int i = threadIdx.x; i < 512; i += 512) sWe[i] = Wenc[i];
    if (threadIdx.x < 64)
        sB[threadIdx.x] = benc[threadIdx.x] + bsrc[threadIdx.x] + bdst[threadIdx.x];
    if (threadIdx.x < 256) sBg[threadIdx.x] = bgate[threadIdx.x];
    __syncthreads();

    const int wid = threadIdx.x >> 6, lane = threadIdx.x & 63;
    const int i64s = sFl[0], i64d = sFl[1];

    for (int e = blockIdx.x * 8 + wid; e < E; e += gridDim.x * 8) {
        const int s = i64s ? src[2 * e] : src[e];
        const int t = i64d ? dst[2 * e] : dst[e];
        if (s < 0 || s >= N || t < 0 || t >= N) continue;

        const float es = emb[s * 64 + lane];
        const float et = emb[t * 64 + lane];
        float de = sB[lane];
        #pragma unroll 8
        for (int k = 0; k < 64; ++k) {
            de += __shfl(es, k, 64) * sWsrc[(k << 6) + lane];
            de += __shfl(et, k, 64) * sWdst[(k << 6) + lane];
        }
        const float r0 = r_ij[e * 3 + 0];
        const float r1 = r_ij[e * 3 + 1];
        const float r2 = r_ij[e * 3 + 2];
        const float d = sqrtf(r0 * r0 + r1 * r1 + r2 * r2);
        #pragma unroll
        for (int m = 0; m < 8; ++m) {
            const float mu = (2.0f / 7.0f) * (float)m;
            const float tt = (d - mu) * 4.0f;
            de += __expf(-tt * tt) * sWe[m * 64 + lane];
        }

        const float v0 = r0 * 3.5f, v1 = r1 * 3.5f, v2 = r2 * 3.5f;
        const float inv = rsqrtf(1.0f + v0 * v0 + v1 * v1 + v2 * v2);
        const float h0 = v0 * inv, h1 = v1 * inv, h2 = v2 * inv;

        const float z0v = z0g[t * 64 + lane];
        const float za = z1g[t * 192 + lane];
        const float zb = z1g[t * 192 + 64 + lane];
        const float zc = z1g[t * 192 + 128 + lane];
        const float uu = h0 * za + h1 * zb + h2 * zc;

        float g0 = sBg[lane], g1 = sBg[64 + lane], g2 = sBg[128 + lane], g3 = sBg[192 + lane];
        #pragma unroll 8
        for (int k = 0; k < 64; ++k) {
            const float dk = __shfl(de, k, 64);
            const float* w = &sWg[(k << 8) + lane];
            g0 += dk * w[0];
            g1 += dk * w[64];
            g2 += dk * w[128];
            g3 += dk * w[192];
        }

        const float smsg = g0 * z0v + g1 * uu;
        const float vm0 = g2 * za + g3 * h0 * z0v;
        const float vm1 = g2 * zb + g3 * h1 * z0v;
        const float vm2 = g2 * zc + g3 * h2 * z0v;

        float p0 = 0.f, q0 = 0.f, q1 = 0.f, q2 = 0.f;
        #pragma unroll 8
        for (int k = 0; k < 64; ++k) {
            const float sk = __shfl(smsg, k, 64);
            const float a = __shfl(vm0, k, 64);
            const float b = __shfl(vm1, k, 64);
            const float c = __shfl(vm2, k, 64);
            p0 += sk * sWs[(k << 6) + lane];
            const float wv = sWv[(k << 6) + lane];
            q0 += a * wv;
            q1 += b * wv;
            q2 += c * wv;
        }

        atomicAdd(&out[s * 64 + lane], p0);
        const int b1 = N * 64 + s * 192 + lane;
        atomicAdd(&out[b1], q0);
        atomicAdd(&out[b1 + 64], q1);
        atomicAdd(&out[b1 + 128], q2);
    }
}

extern "C" void kernel_launch(void* const* d_in, const int* in_sizes, int n_in,
                              void* d_out, int out_size, void* d_ws, size_t ws_size,
                              hipStream_t stream) {
    const int* src = (const int*)d_in[0];
    const int* dst = (const int*)d_in[1];
    const float* r_ij = (const float*)d_in[2];
    const float* z0g  = (const float*)d_in[3];
    const float* z1g  = (const float*)d_in[4];
    const float* emb  = (const float*)d_in[5];
    const float* Wenc = (const float*)d_in[6];
    const float* benc = (const float*)d_in[7];
    const float* Wsrc = (const float*)d_in[8];
    const float* bsrc = (const float*)d_in[9];
    const float* Wdst = (const float*)d_in[10];
    const float* bdst = (const float*)d_in[11];
    const float* Wgate = (const float*)d_in[12];
    const float* bgate = (const float*)d_in[13];
    const float* Ws = (const float*)d_in[14];
    const float* Wv = (const float*)d_in[15];

    const int N = out_size / 256;                    // out0 N*64 + out1 N*192
    int E = in_sizes[0];
    if (in_sizes[2] / 3 < E) E = in_sizes[2] / 3;    // robustness

    float* ws = (float*)d_ws;
    // HG: N*512 half = N*256 float slots; HZ: N*256 half = N*128 slots;
    // ACC: N*256 half = N*128 slots  -> total N*512 float slots.
    const size_t need = ((size_t)WS_GS + (size_t)N * 512u + 16u) * sizeof(float);

    if (ws != nullptr && ws_size >= need) {
        compose_k<<<73, 256, 0, stream>>>(Wsrc, Wdst, Wenc, benc, bsrc, bdst,
                                          Wgate, bgate, ws);
        h16* HG = (h16*)(ws + WS_GS);
        h16* HZ = HG + (size_t)N * 512;
        h16* ACC = HZ + (size_t)N * 256;
        zero_k<<<1024, 256, 0, stream>>>((float*)ACC, N * 128);  // 26 MB, not 51
        nodepre3_k<<<256, 512, 0, stream>>>(emb, ws + WS_WSG, HG, N);
        hz_k<<<1024, 256, 0, stream>>>(z0g, z1g, HZ, N);
        edge_pk_k<<<2048, 256, 0, stream>>>(src, dst, r_ij, HG, HZ,
                                            ws + WS_WEG, ws + WS_BALL,
                                            ACC, N, E);
        nodepost4_k<<<2048, 256, 0, stream>>>(ACC, (float*)d_out, Ws, Wv, N);
    } else {
        zero_k<<<2048, 256, 0, stream>>>((float*)d_out, out_size);
        edge_k<<<2048, 512, 0, stream>>>(src, dst, r_ij, z0g, z1g, emb, Wenc, benc,
                                         Wsrc, bsrc, Wdst, bdst, Wgate, bgate, Ws, Wv,
                                         (float*)d_out, N, E);
    }
}